// Round 8
// baseline (1318.180 us; speedup 1.0000x reference)
//
#include <hip/hip_runtime.h>
#include <hip/hip_bf16.h>
#include <math.h>

// Problem constants
#define Bd 8
#define Nd 1024
#define Hd 200
#define HP 224                      // Hd padded to multiple of 32
#define BN (Bd*Nd)                  // 8192
#define SZ_BNH ((size_t)BN*Hd)      // 1,638,400
#define SZ_BNN ((size_t)BN*Nd)      // 8,388,608
#define SZ_PAD ((size_t)BN*HP)      // 1,835,008

typedef __hip_bfloat16 bf16;
typedef __attribute__((ext_vector_type(8))) short bf16x8;   // 8 bf16 = 4 VGPRs (A/B frag)
typedef __attribute__((ext_vector_type(4))) float f32x4;    // C/D frag
typedef __attribute__((ext_vector_type(4))) short s16x4;    // 4 bf16 = 8B store

__device__ __forceinline__ float bf2f(bf16 v){ return __bfloat162float(v); }
__device__ __forceinline__ bf16 f2bf(float v){ return __float2bfloat16(v); }
__device__ __forceinline__ short bfb(float v){ bf16 h = f2bf(v); return *(short*)&h; }
__device__ __forceinline__ short lowb(float v){
  bf16 h = f2bf(v); bf16 l = f2bf(v - bf2f(h)); return *(short*)&l;
}

#define MFMA16(a,b,c) __builtin_amdgcn_mfma_f32_16x16x32_bf16((a),(b),(c),0,0,0)

// Fragment-native tiled layout. Element (row, k) of a [R][KP] matrix lives at:
//   (row>>4)*16*KP + (k>>5)*512 + ((k>>3)&3)*128 + (row&15)*8 + (k&7)
__device__ __forceinline__ size_t tidx1024(int row, int k){
  return (size_t)(row>>4)*16384 + (size_t)((k>>5))*512
       + (size_t)(((k>>3)&3))*128 + (size_t)(row&15)*8 + (k&7);
}
__device__ __forceinline__ size_t tidxHP(int row, int k){
  return (size_t)(row>>4)*3584 + (size_t)((k>>5))*512
       + (size_t)(((k>>3)&3))*128 + (size_t)(row&15)*8 + (k&7);
}

// ============================ prep (fp32) ============================
__global__ void k_prep_masks(const float* __restrict__ tm, float* __restrict__ maskf,
                             float* __restrict__ maskadd){
  int i = blockIdx.x*256 + threadIdx.x;
  if (i < BN){ float m = tm[i]; maskf[i] = m; maskadd[i] = (1.f - m) * -10000.f; }
}

__global__ void k_prep_adj(const float* __restrict__ a1, const float* __restrict__ a2,
                           float* __restrict__ adj_out, float* __restrict__ denom){
  int r = blockIdx.x;
  const size_t base = (size_t)r * Nd;
  int t = threadIdx.x;
  float s = 0.f;
  for (int m = t; m < Nd; m += 256){
    float a = a1[base+m] + a2[base+m];
    a = a >= 1.f ? 1.f : a;
    adj_out[base+m] = a;
    s += a;
  }
  __shared__ float red[256];
  red[t] = s; __syncthreads();
  for (int st = 128; st > 0; st >>= 1){ if (t < st) red[t] += red[t+st]; __syncthreads(); }
  if (t == 0) denom[r] = red[0] + 1e-07f;
}

__global__ void k_copy2(const float* __restrict__ x, float* __restrict__ o1,
                        float* __restrict__ o2){
  size_t i = (size_t)blockIdx.x*256 + threadIdx.x;
  if (i < SZ_BNH){ float v = x[i]; o1[i] = v; o2[i] = v; }
}

// ============================ split conversions ============================
__global__ void c_pad_split(const float* __restrict__ X, bf16* __restrict__ Oh,
                            bf16* __restrict__ Ol){
  size_t o = (size_t)blockIdx.x*256 + threadIdx.x;
  if (o >= SZ_PAD) return;
  int oi = (int)o;
  int panel = oi / 3584;             // 16*HP
  int rem   = oi % 3584;
  int kt  = rem >> 9;
  int kg  = (rem >> 7) & 3;
  int r16 = (rem >> 3) & 15;
  int ke  = rem & 7;
  int row = panel*16 + r16;
  int k   = kt*32 + kg*8 + ke;
  float v = (k < Hd) ? X[(size_t)row*Hd + k] : 0.f;
  bf16 h = f2bf(v);
  Oh[o] = h; Ol[o] = f2bf(v - bf2f(h));
}

// Transpose-pad-split writing the TILED-1024 layout (row = d, k = m).
__global__ void c_padT_split(const float* __restrict__ X, bf16* __restrict__ Oh,
                             bf16* __restrict__ Ol){
  __shared__ float t[32][33];
  int b = blockIdx.z, m0 = blockIdx.x*32, d0 = blockIdx.y*32;
  int tx = threadIdx.x, ty = threadIdx.y;          // block (32,8)
  for (int i = ty; i < 32; i += 8){
    int d = d0 + tx;
    t[i][tx] = (d < Hd) ? X[((size_t)b*Nd + m0+i)*Hd + d] : 0.f;
  }
  __syncthreads();
  for (int i = ty; i < 32; i += 8){
    int row = d0 + i, kk = m0 + tx;
    size_t idx = (size_t)b*229376 + tidx1024(row, kk);
    float v = t[tx][i];
    bf16 h = f2bf(v);
    Oh[idx] = h; Ol[idx] = f2bf(v - bf2f(h));
  }
}

// Batched weight split -> TILED layout.
// mi: 0=gcn 1=mut 2..4=qw 5..7=kw 8..10=vw 11..13=aow 14..16=iw 17..19=ow
__global__ void c_w_split_all(const float* __restrict__ g, const float* __restrict__ m,
                              const float* __restrict__ q, const float* __restrict__ k,
                              const float* __restrict__ v, const float* __restrict__ ao,
                              const float* __restrict__ iw, const float* __restrict__ ow,
                              bf16* __restrict__ Oh, bf16* __restrict__ Ol){
  int mi = blockIdx.y;
  const float* W;
  if (mi == 0) W = g;
  else if (mi == 1) W = m;
  else {
    int gi = (mi-2)/3, si = (mi-2)%3;
    const float* bs[6] = {q, k, v, ao, iw, ow};
    W = bs[gi] + (size_t)si*Hd*Hd;
  }
  int o = blockIdx.x*256 + threadIdx.x;
  if (o >= HP*HP) return;
  int panel = o / 3584;
  int rem   = o % 3584;
  int kt  = rem >> 9;
  int kg  = (rem >> 7) & 3;
  int r16 = (rem >> 3) & 15;
  int ke  = rem & 7;
  int n   = panel*16 + r16;          // output col (B-matrix row)
  int kk  = kt*32 + kg*8 + ke;
  float val = (n < Hd && kk < Hd) ? W[kk*Hd + n] : 0.f;
  bf16 h = f2bf(val);
  Oh[(size_t)mi*HP*HP + o] = h; Ol[(size_t)mi*HP*HP + o] = f2bf(val - bf2f(h));
}

// adj -> bf16 tiled-1024 (once; adj constant across iterations).
__global__ void c_cvt1024_t(const float* __restrict__ X, bf16* __restrict__ O){
  int b = blockIdx.z, kg = blockIdx.x, rg = blockIdx.y;
  int r = threadIdx.x >> 5, kl = threadIdx.x & 31;
  int row = rg*8 + r, k = kg*32 + kl;
  float v = X[(size_t)b*1048576 + (size_t)row*1024 + k];
  O[(size_t)b*1048576 + tidx1024(row, k)] = f2bf(v);
}

// ============================ fused row softmax ============================
// Register-resident: thread t owns elements 4t..4t+3 of its row (one float4).
// SPLIT=0: single-bf16 p_row (attention). SPLIT=2: Dekker p_row pair PLUS
// column-softmax transposed pair (p_col^T) using precomputed cmax/csum.
// exp cached in registers for p_row (1 __expf per element); p_col recomputes
// its own __expf (row-max/col-max rescale trick would NaN on masked columns).
template<int SPLIT>
__global__ __launch_bounds__(256)
void k_rowsoftmax(const float* __restrict__ S, bf16* __restrict__ Ph,
                  bf16* __restrict__ Pl, const float* __restrict__ cmax,
                  const float* __restrict__ csum, bf16* __restrict__ PcH,
                  bf16* __restrict__ PcL){
  __shared__ float red[256];
  size_t bid = blockIdx.x;
  size_t r = ((bid & 7) << 10) + (bid >> 3);     // batch = bid&7, slot = bid>>3
  int t = threadIdx.x;
  const f32x4 v4 = *(const f32x4*)(S + r*Nd + t*4);
  float mx = fmaxf(fmaxf(v4[0], v4[1]), fmaxf(v4[2], v4[3]));
  red[t] = mx; __syncthreads();
  for (int s = 128; s > 0; s >>= 1){ if (t < s) red[t] = fmaxf(red[t], red[t+s]); __syncthreads(); }
  mx = red[0]; __syncthreads();
  float e0 = __expf(v4[0] - mx), e1 = __expf(v4[1] - mx);
  float e2 = __expf(v4[2] - mx), e3 = __expf(v4[3] - mx);
  red[t] = (e0 + e1) + (e2 + e3); __syncthreads();
  for (int s = 128; s > 0; s >>= 1){ if (t < s) red[t] += red[t+s]; __syncthreads(); }
  float inv = 1.f / red[0];
  size_t obase = ((r >> 10) << 20) + (size_t)(((int)(r & 1023)) >> 4)*16384
               + (size_t)((int)r & 15)*8;
  {
    int i = t*4;
    size_t idx = obase + (size_t)(i>>5)*512 + (size_t)((i>>3)&3)*128 + (i&7);
    float p0 = e0*inv, p1 = e1*inv, p2 = e2*inv, p3 = e3*inv;
    s16x4 hv = { bfb(p0), bfb(p1), bfb(p2), bfb(p3) };
    *(s16x4*)(Ph + idx) = hv;
    if (SPLIT == 2){
      s16x4 lv = { lowb(p0), lowb(p1), lowb(p2), lowb(p3) };
      *(s16x4*)(Pl + idx) = lv;
    }
  }
  if (SPLIT == 2){
    int bq = (int)(r >> 10);
    int n  = (int)(r & 1023);
    int m0 = t*4;
    const f32x4 c4 = *(const f32x4*)(cmax + bq*Nd + m0);
    const f32x4 s4 = *(const f32x4*)(csum + bq*Nd + m0);
    size_t base = (size_t)bq*1048576 + (size_t)(m0>>4)*16384 + (size_t)(n>>5)*512
                + (size_t)((n>>3)&3)*128 + (size_t)(m0&15)*8 + (size_t)(n&7);
    #pragma unroll
    for (int j = 0; j < 4; j++){
      float ci = 1.f / s4[j];
      float p = __expf(v4[j] - c4[j]) * ci;
      bf16 h = f2bf(p);
      PcH[base + j*8] = h;
      PcL[base + j*8] = f2bf(p - bf2f(h));
    }
  }
}

// Combine 8 per-rowblock column partials into final column stats.
__global__ void k_colcomb(const float* __restrict__ cpm, const float* __restrict__ cps,
                          float* __restrict__ cmax, float* __restrict__ csum){
  int i = blockIdx.x*256 + threadIdx.x;    // global col b*1024+m
  float M = cpm[i], S = cps[i];
  #pragma unroll
  for (int y = 1; y < 8; y++){
    float m2 = cpm[(size_t)y*BN + i], s2 = cps[(size_t)y*BN + i];
    float Mn = fmaxf(M, m2);
    S = S*__expf(M - Mn) + s2*__expf(m2 - Mn);
    M = Mn;
  }
  cmax[i] = M; csum[i] = S;
}

// ============================ residual + layernorm (+ optional pair out) =========
__global__ void k_add_ln(const float* __restrict__ X, const float* __restrict__ R,
                         const float* __restrict__ g, const float* __restrict__ bb,
                         float* __restrict__ Y, bf16* __restrict__ Ph,
                         bf16* __restrict__ Pl){
  int r = blockIdx.x, t = threadIdx.x;
  __shared__ float red[256];
  bool act = t < Hd;
  float v = 0.f;
  if (act) v = X[(size_t)r*Hd + t] + R[(size_t)r*Hd + t];
  red[t] = act ? v : 0.f; __syncthreads();
  for (int s = 128; s > 0; s >>= 1){ if (t < s) red[t] += red[t+s]; __syncthreads(); }
  float mu = red[0] * (1.f/Hd); __syncthreads();
  float d = act ? (v - mu) : 0.f;
  red[t] = d*d; __syncthreads();
  for (int s = 128; s > 0; s >>= 1){ if (t < s) red[t] += red[t+s]; __syncthreads(); }
  float var = red[0] * (1.f/Hd);
  float o = 0.f;
  if (act){
    float rs = 1.f / sqrtf(var + 1e-20f);
    o = (v - mu) * rs * g[t] + bb[t];
    Y[(size_t)r*Hd + t] = o;
  }
  if (Ph && t < HP){
    bf16 h = f2bf(o);
    size_t idx = tidxHP(r, t);
    Ph[idx] = h; Pl[idx] = f2bf(o - bf2f(h));
  }
}

// ============================ merged Q/K/V GEMM ============================
// blockIdx.z = slice: 0=Q (pair->QH/QL), 1=K (pair->KH/KL), 2=V (transposed pair
// ->VH/VL via LDS). Weight slot base Wh0/Wl0 = Q slot; slice stride 3 slots.
__global__ __launch_bounds__(256)
void k_qkv(const bf16* __restrict__ Ah, const bf16* __restrict__ Al,
           const bf16* __restrict__ Wh0, const bf16* __restrict__ Wl0,
           bf16* __restrict__ QH, bf16* __restrict__ QL,
           bf16* __restrict__ KH, bf16* __restrict__ KL,
           bf16* __restrict__ VH, bf16* __restrict__ VL,
           const float* __restrict__ qb, const float* __restrict__ kb,
           const float* __restrict__ vb)
{
  constexpr int KP = HP;
  constexpr int STEPS = KP/32;
  int slice = blockIdx.z;
  int wave = threadIdx.x >> 6, lane = threadIdx.x & 63;
  int r0 = (blockIdx.y*4 + wave)*16;
  int c0 = blockIdx.x*64;
  int lm = lane & 15, lq = lane >> 4;
  const size_t PST = (size_t)16*KP;
  const size_t aT = (size_t)(r0>>4)*PST + (size_t)lane*8;
  const size_t bT = (size_t)slice*3*HP*HP + (size_t)(c0>>4)*PST + (size_t)lane*8;

  f32x4 acc[4] = {};
  bf16x8 pah[2], pal[2], pbh[2][4], pbl[2][4];
  pah[0] = *(const bf16x8*)(Ah + aT);
  pal[0] = *(const bf16x8*)(Al + aT);
  #pragma unroll
  for (int j = 0; j < 4; j++){
    pbh[0][j] = *(const bf16x8*)(Wh0 + bT + (size_t)j*PST);
    pbl[0][j] = *(const bf16x8*)(Wl0 + bT + (size_t)j*PST);
  }
  #pragma unroll
  for (int ki = 0; ki < STEPS; ki++){
    const int cb = ki & 1, nb = cb ^ 1;
    if (ki + 1 < STEPS){
      const size_t kn = (size_t)(ki+1)*512;
      pah[nb] = *(const bf16x8*)(Ah + aT + kn);
      pal[nb] = *(const bf16x8*)(Al + aT + kn);
      #pragma unroll
      for (int j = 0; j < 4; j++){
        pbh[nb][j] = *(const bf16x8*)(Wh0 + bT + (size_t)j*PST + kn);
        pbl[nb][j] = *(const bf16x8*)(Wl0 + bT + (size_t)j*PST + kn);
      }
    }
    #pragma unroll
    for (int j = 0; j < 4; j++) acc[j] = MFMA16(pah[cb], pbh[cb][j], acc[j]);
    #pragma unroll
    for (int j = 0; j < 4; j++) acc[j] = MFMA16(pah[cb], pbl[cb][j], acc[j]);
    #pragma unroll
    for (int j = 0; j < 4; j++) acc[j] = MFMA16(pal[cb], pbh[cb][j], acc[j]);
  }

  const float* bias = (slice == 0) ? qb : (slice == 1) ? kb : vb;
  if (slice < 2){
    bf16* Oh = (slice == 0) ? QH : KH;
    bf16* Ol = (slice == 0) ? QL : KL;
    #pragma unroll
    for (int j = 0; j < 4; j++){
      int col = c0 + j*16 + lm;
      if (col >= HP) continue;
      #pragma unroll
      for (int r = 0; r < 4; r++){
        int row = r0 + lq*4 + r;
        float o = (col < Hd) ? acc[j][r] + bias[col] : 0.f;
        bf16 h = f2bf(o);
        size_t idx = tidxHP(row, col);
        Oh[idx] = h; Ol[idx] = f2bf(o - bf2f(h));
      }
    }
  } else {
    __shared__ float tl[64][65];
    #pragma unroll
    for (int j = 0; j < 4; j++)
      #pragma unroll
      for (int r = 0; r < 4; r++)
        tl[wave*16 + lq*4 + r][j*16 + lm] = acc[j][r];
    __syncthreads();
    int b2 = (int)((blockIdx.y*64) >> 10);
    int m0 = (int)((blockIdx.y*64) & 1023);
    #pragma unroll
    for (int e = threadIdx.x; e < 4096; e += 256){
      int pan = e >> 10, rem = e & 1023;
      int r16 = (rem >> 3) & 15;
      int d = c0 + pan*16 + r16;
      if (d >= HP) continue;
      int kg = (rem >> 7) & 3;
      int k_loc = (rem >> 9)*32 + kg*8 + (rem & 7);
      float val = 0.f;
      if (d < Hd) val = tl[k_loc][pan*16 + r16] + bias[d];
      bf16 h = f2bf(val);
      size_t idx = (size_t)b2*229376 + (size_t)(d>>4)*16384
                 + (size_t)((m0 + k_loc)>>5)*512 + (size_t)kg*128
                 + (size_t)r16*8 + (rem & 7);
      VH[idx] = h; VL[idx] = f2bf(val - bf2f(h));
    }
  }
}

// ============================ split-precision MFMA GEMM (no split-K) ============
// EPI: 0 fp32 Y=acc+bias   2 split-bf16 row-tiled pair out (+bias)
//      3 S=acc*scale+maskadd[col]   4 S=acc+pairmask (+ column-stats partials)
//      9 TRANSPOSED tiled pair out (+bias) via LDS   10 gelu -> row-tiled pair
template<int EPI, int TERMS, int RI, int KP>
__global__ __launch_bounds__(256)
void k_mfma3(const bf16* __restrict__ Ah, const bf16* __restrict__ Al,
             const bf16* __restrict__ Bh, const bf16* __restrict__ Bl,
             float* __restrict__ Y, bf16* __restrict__ Ybh, bf16* __restrict__ Ybl,
             const float* __restrict__ bias, const float* __restrict__ e0,
             const float* __restrict__ e1,
             size_t sAb, size_t sBb, float scale,
             float* __restrict__ cpm, float* __restrict__ cps)
{
  int b = blockIdx.z;
  int wave = threadIdx.x >> 6, lane = threadIdx.x & 63;
  int r0 = (blockIdx.y*4 + wave)*(RI*16);
  int c0 = blockIdx.x*64;
  int lm = lane & 15, lq = lane >> 4;
  const size_t PST = (size_t)16*KP;     // panel stride (elements)
  const size_t aT = (size_t)b*sAb + (size_t)(r0>>4)*PST + (size_t)lane*8;
  const size_t bT = (size_t)b*sBb + (size_t)(c0>>4)*PST + (size_t)lane*8;
  constexpr int STEPS = KP/32;

  f32x4 acc[RI][4] = {};
  bf16x8 pah[2][RI], pal[2][RI], pbh[2][4], pbl[2][4];
  {
    #pragma unroll
    for (int i = 0; i < RI; i++) pah[0][i] = *(const bf16x8*)(Ah + aT + (size_t)i*PST);
    #pragma unroll
    for (int j = 0; j < 4; j++){
      pbh[0][j] = *(const bf16x8*)(Bh + bT + (size_t)j*PST);
      pbl[0][j] = *(const bf16x8*)(Bl + bT + (size_t)j*PST);
    }
    if (TERMS >= 3){
      #pragma unroll
      for (int i = 0; i < RI; i++) pal[0][i] = *(const bf16x8*)(Al + aT + (size_t)i*PST);
    }
  }

  #pragma unroll
  for (int ki = 0; ki < STEPS; ki++){
    const int cb = ki & 1, nb = cb ^ 1;
    if (ki + 1 < STEPS){
      const size_t kn = (size_t)(ki+1)*512;
      #pragma unroll
      for (int i = 0; i < RI; i++) pah[nb][i] = *(const bf16x8*)(Ah + aT + (size_t)i*PST + kn);
      #pragma unroll
      for (int j = 0; j < 4; j++){
        pbh[nb][j] = *(const bf16x8*)(Bh + bT + (size_t)j*PST + kn);
        pbl[nb][j] = *(const bf16x8*)(Bl + bT + (size_t)j*PST + kn);
      }
      if (TERMS >= 3){
        #pragma unroll
        for (int i = 0; i < RI; i++) pal[nb][i] = *(const bf16x8*)(Al + aT + (size_t)i*PST + kn);
      }
    }
    #pragma unroll
    for (int i = 0; i < RI; i++)
      #pragma unroll
      for (int j = 0; j < 4; j++) acc[i][j] = MFMA16(pah[cb][i], pbh[cb][j], acc[i][j]);
    #pragma unroll
    for (int i = 0; i < RI; i++)
      #pragma unroll
      for (int j = 0; j < 4; j++) acc[i][j] = MFMA16(pah[cb][i], pbl[cb][j], acc[i][j]);
    if (TERMS >= 3){
      #pragma unroll
      for (int i = 0; i < RI; i++)
        #pragma unroll
        for (int j = 0; j < 4; j++) acc[i][j] = MFMA16(pal[cb][i], pbh[cb][j], acc[i][j]);
    }
  }

  if constexpr (EPI == 9){
    __shared__ float tl[64][65];
    #pragma unroll
    for (int j = 0; j < 4; j++)
      #pragma unroll
      for (int r = 0; r < 4; r++)
        tl[wave*16 + lq*4 + r][j*16 + lm] = acc[0][j][r];
    __syncthreads();
    int b2 = (int)((blockIdx.y*64) >> 10);
    int m0 = (int)((blockIdx.y*64) & 1023);
    #pragma unroll
    for (int e = threadIdx.x; e < 4096; e += 256){
      int pan = e >> 10, rem = e & 1023;
      int r16 = (rem >> 3) & 15;
      int d = c0 + pan*16 + r16;
      if (d >= HP) continue;
      int kg = (rem >> 7) & 3;
      int k_loc = (rem >> 9)*32 + kg*8 + (rem & 7);
      float val = 0.f;
      if (d < Hd) val = tl[k_loc][pan*16 + r16] + (bias ? bias[d] : 0.f);
      bf16 h = f2bf(val);
      size_t idx = (size_t)b2*229376 + (size_t)(d>>4)*16384
                 + (size_t)((m0 + k_loc)>>5)*512 + (size_t)kg*128
                 + (size_t)r16*8 + (rem & 7);
      Ybh[idx] = h; Ybl[idx] = f2bf(val - bf2f(h));
    }
  } else if constexpr (EPI == 4){
    // logits + per-block column-softmax partials (max, sum-exp over 128 rows)
    float er[RI][4];
    #pragma unroll
    for (int i = 0; i < RI; i++)
      #pragma unroll
      for (int r = 0; r < 4; r++)
        er[i][r] = e1[b*Nd + r0 + i*16 + lq*4 + r];
    float cm[4], cs[4];
    #pragma unroll
    for (int j = 0; j < 4; j++){
      int col = c0 + j*16 + lm;
      float e1c = e1[b*Nd + col];
      float wv[RI][4];
      float mloc = -3.4e38f;
      #pragma unroll
      for (int i = 0; i < RI; i++){
        #pragma unroll
        for (int r = 0; r < 4; r++){
          int row = r0 + i*16 + lq*4 + r;
          float w = acc[i][j][r] + (1.f - er[i][r]*e1c)*(-10000.f);
          Y[((size_t)b*Nd + row)*Nd + col] = w;
          wv[i][r] = w;
          mloc = fmaxf(mloc, w);
        }
      }
      float sloc = 0.f;
      #pragma unroll
      for (int i = 0; i < RI; i++)
        #pragma unroll
        for (int r = 0; r < 4; r++) sloc += __expf(wv[i][r] - mloc);
      cm[j] = mloc; cs[j] = sloc;
    }
    #pragma unroll
    for (int j = 0; j < 4; j++){
      float m = cm[j], s = cs[j];
      #pragma unroll
      for (int off = 16; off <= 32; off <<= 1){
        float m2 = __shfl_xor(m, off), s2 = __shfl_xor(s, off);
        float M = fmaxf(m, m2);
        s = s*__expf(m - M) + s2*__expf(m2 - M);
        m = M;
      }
      cm[j] = m; cs[j] = s;
    }
    __shared__ float pmx[4][4][16], psm[4][4][16];
    if (lq == 0){
      #pragma unroll
      for (int j = 0; j < 4; j++){ pmx[wave][j][lm] = cm[j]; psm[wave][j][lm] = cs[j]; }
    }
    __syncthreads();
    if (threadIdx.x < 64){
      int t = threadIdx.x;             // col-in-block = t (j=t>>4, lm=t&15)
      int jj = t >> 4, cc = t & 15;
      float M = pmx[0][jj][cc], S = psm[0][jj][cc];
      #pragma unroll
      for (int w = 1; w < 4; w++){
        float m2 = pmx[w][jj][cc], s2 = psm[w][jj][cc];
        float Mn = fmaxf(M, m2);
        S = S*__expf(M - Mn) + s2*__expf(m2 - Mn);
        M = Mn;
      }
      size_t pi = (size_t)blockIdx.y*BN + (size_t)b*Nd + c0 + t;
      cpm[pi] = M; cps[pi] = S;
    }
  } else {
    #pragma unroll
    for (int i = 0; i < RI; i++){
      #pragma unroll
      for (int j = 0; j < 4; j++){
        int col = c0 + j*16 + lm;
        int rbase = r0 + i*16 + lq*4;
        #pragma unroll
        for (int r = 0; r < 4; r++){
          int row = rbase + r;
          size_t rowg = (size_t)b*Nd + row;
          float v = acc[i][j][r];
          if (EPI == 0){
            if (col < Hd){
              v += bias ? bias[col] : 0.f;
              Y[rowg*Hd + col] = v;
            }
          } else if (EPI == 2){
            if (col < HP){
              float o = (col < Hd) ? v + (bias ? bias[col] : 0.f) : 0.f;
              bf16 h = f2bf(o);
              size_t idx = tidxHP((int)rowg, col);
              Ybh[idx] = h;
              Ybl[idx] = f2bf(o - bf2f(h));
            }
          } else if (EPI == 3){
            Y[rowg*Nd + col] = v*scale + e0[b*Nd + col];
          } else if (EPI == 10){
            if (col < HP){
              float o = 0.f;
              if (col < Hd){
                float vv = v + (bias ? bias[col] : 0.f);
                o = 0.5f*vv*(1.f + erff(vv*0.7071067811865476f));
              }
              bf16 h = f2bf(o);
              size_t idx = tidxHP((int)rowg, col);
              Ybh[idx] = h;
              Ybl[idx] = f2bf(o - bf2f(h));
            }
          }
        }
      }
    }
  }
}

// ============================ split-K=4 MFMA GEMM (K=1024 mixes) ================
// EPI: 5 Y+=relu(acc/denom[row]) + pair   6 Y=acc*maskf[row]+R + pair
//      7 Y=acc*maskf[row]+Y + pair        8 pair only (ctx)
// Optional TbH/TbL: ALSO write the transposed tiled-1024 pair (d=col, k=row).
template<int EPI, int TERMS, int KP>
__global__ __launch_bounds__(256)
void k_mfma3sk(const bf16* __restrict__ Ah, const bf16* __restrict__ Al,
               const bf16* __restrict__ Bh, const bf16* __restrict__ Bl,
               float* __restrict__ Y, bf16* __restrict__ Ybh, bf16* __restrict__ Ybl,
               const float* __restrict__ e0, const float* __restrict__ e1,
               const float* __restrict__ R,
               size_t sAb, size_t sBb,
               bf16* __restrict__ TbH, bf16* __restrict__ TbL)
{
  __shared__ float red[4][64][33];
  int b = blockIdx.z;
  int wave = threadIdx.x >> 6, lane = threadIdx.x & 63;
  int r0 = blockIdx.x*32;
  int c0 = blockIdx.y*64;
  int lm = lane & 15, lq = lane >> 4;
  const size_t aT = (size_t)b*sAb + (size_t)(r0>>4)*((size_t)16*KP) + (size_t)lane*8;
  const size_t bT = (size_t)b*sBb + (size_t)(c0>>4)*((size_t)16*KP) + (size_t)lane*8;
  const int kt0 = wave*(KP>>7);
  constexpr int STEPS = KP/128;

  f32x4 acc[2][4] = {};
  bf16x8 pah[2][2], pal[2][2], pbh[2][4], pbl[2][4];
  {
    const size_t ko = (size_t)kt0*512;
    #pragma unroll
    for (int i = 0; i < 2; i++) pah[0][i] = *(const bf16x8*)(Ah + aT + (size_t)(i*16)*KP + ko);
    #pragma unroll
    for (int j = 0; j < 4; j++){
      pbh[0][j] = *(const bf16x8*)(Bh + bT + (size_t)(j*16)*KP + ko);
      pbl[0][j] = *(const bf16x8*)(Bl + bT + (size_t)(j*16)*KP + ko);
    }
    if (TERMS >= 3){
      #pragma unroll
      for (int i = 0; i < 2; i++) pal[0][i] = *(const bf16x8*)(Al + aT + (size_t)(i*16)*KP + ko);
    }
  }

  #pragma unroll
  for (int ki = 0; ki < STEPS; ki++){
    const int cb = ki & 1, nb = cb ^ 1;
    if (ki + 1 < STEPS){
      const size_t kn = (size_t)(kt0 + ki + 1)*512;
      #pragma unroll
      for (int i = 0; i < 2; i++) pah[nb][i] = *(const bf16x8*)(Ah + aT + (size_t)(i*16)*KP + kn);
      #pragma unroll
      for (int j = 0; j < 4; j++){
        pbh[nb][j] = *(const bf16x8*)(Bh + bT + (size_t)(j*16)*KP + kn);
        pbl[nb][j] = *(const bf16x8*)(Bl + bT + (size_t)(j*16)*KP + kn);
      }
      if (TERMS >= 3){
        #pragma unroll
        for (int i = 0; i < 2; i++) pal[nb][i] = *(const bf16x8*)(Al + aT + (size_t)(i*16)*KP + kn);
      }
    }
    #pragma unroll
    for (int i = 0; i < 2; i++)
      #pragma unroll
      for (int j = 0; j < 4; j++) acc[i][j] = MFMA16(pah[cb][i], pbh[cb][j], acc[i][j]);
    #pragma unroll
    for (int i = 0; i < 2; i++)
      #pragma unroll
      for (int j = 0; j < 4; j++) acc[i][j] = MFMA16(pah[cb][i], pbl[cb][j], acc[i][j]);
    if (TERMS >= 3){
      #pragma unroll
      for (int i = 0; i < 2; i++)
        #pragma unroll
        for (int j = 0; j < 4; j++) acc[i][j] = MFMA16(pal[cb][i], pbh[cb][j], acc[i][j]);
    }
  }

  #pragma unroll
  for (int i = 0; i < 2; i++)
    #pragma unroll
    for (int j = 0; j < 4; j++)
      #pragma unroll
      for (int r = 0; r < 4; r++)
        red[wave][lane][i*16 + j*4 + r] = acc[i][j][r];
  __syncthreads();

  int iw = wave >> 1, j0 = (wave & 1)*2;
  #pragma unroll
  for (int jj = 0; jj < 2; jj++){
    int j = j0 + jj;
    int col = c0 + j*16 + lm;
    #pragma unroll
    for (int r = 0; r < 4; r++){
      int f = iw*16 + j*4 + r;
      float v = red[0][lane][f] + red[1][lane][f] + red[2][lane][f] + red[3][lane][f];
      int row = r0 + iw*16 + lq*4 + r;
      size_t rowg = (size_t)b*Nd + row;
      if (col < HP){
        float nv = 0.f;
        if (EPI == 8){
          nv = (col < Hd) ? v : 0.f;
        } else if (EPI == 5){
          if (col < Hd){
            float u = v / e0[b*Nd+row]; u = u > 0.f ? u : 0.f;
            nv = Y[rowg*Hd + col] + u;
            Y[rowg*Hd + col] = nv;
          }
        } else if (EPI == 6){
          if (col < Hd){
            nv = v*e1[b*Nd+row] + R[rowg*Hd+col];
            Y[rowg*Hd + col] = nv;
          }
        } else if (EPI == 7){
          if (col < Hd){
            nv = v*e1[b*Nd+row] + Y[rowg*Hd+col];
            Y[rowg*Hd + col] = nv;
          }
        }
        bf16 h = f2bf(nv);
        bf16 lo = f2bf(nv - bf2f(h));
        size_t idx = tidxHP((int)rowg, col);
        Ybh[idx] = h; Ybl[idx] = lo;
        if (TbH != nullptr){
          size_t idx2 = (size_t)b*((size_t)HP*Nd) + tidx1024(col, row);
          TbH[idx2] = h; TbL[idx2] = lo;
        }
      }
    }
  }
}

// ============================ host launch ============================
static inline char* carve(char*& p, size_t bytes){
  char* r = p;
  p += (bytes + 511) & ~(size_t)511;
  return r;
}

extern "C" void kernel_launch(void* const* d_in, const int* in_sizes, int n_in,
                              void* d_out, int out_size, void* d_ws, size_t ws_size,
                              hipStream_t stream){
  (void)in_sizes; (void)n_in; (void)out_size; (void)ws_size;
  const float* text     = (const float*)d_in[0];
  const float* adj1     = (const float*)d_in[1];
  const float* adj2     = (const float*)d_in[2];
  const float* textmask = (const float*)d_in[5];
  const float* gcn_w    = (const float*)d_in[6];
  const float* mut_w    = (const float*)d_in[7];
  const float* qw = (const float*)d_in[8],  *qb = (const float*)d_in[9];
  const float* kw = (const float*)d_in[10], *kb = (const float*)d_in[11];
  const float* vw = (const float*)d_in[12], *vb = (const float*)d_in[13];
  const float* aow= (const float*)d_in[14], *aob= (const float*)d_in[15];
  const float* g1 = (const float*)d_in[16], *b1 = (const float*)d_in[17];
  const float* iw = (const float*)d_in[18], *ib = (const float*)d_in[19];
  const float* ow = (const float*)d_in[20], *ob = (const float*)d_in[21];
  const float* g2 = (const float*)d_in[22], *b2 = (const float*)d_in[23];

  float* out_outs = (float*)d_out;
  float* out_adj  = out_outs + SZ_BNH;

  // ---- workspace carve (~190 MB). out_outs doubles as fp32 scratch sc2. ----
  char* p = (char*)d_ws;
  float* cur  = (float*)carve(p, SZ_BNH*4);
  float* sc1  = (float*)carve(p, SZ_BNH*4);
  float* fo   = (float*)carve(p, SZ_BNH*4);
  float* S    = (float*)carve(p, SZ_BNN*4);           // fp32 scores / logits
  bf16*  Rb   = (bf16*)carve(p, SZ_BNN*2*2);          // attnP / p_row pair
  bf16*  Rc   = (bf16*)carve(p, SZ_BNN*2*2);          // p_col^T pair
  bf16*  T1   = (bf16*)carve(p, SZ_PAD*2);
  bf16*  T2   = (bf16*)carve(p, SZ_PAD*2);
  bf16*  T3   = (bf16*)carve(p, SZ_PAD*2);
  bf16*  T4   = (bf16*)carve(p, SZ_PAD*2);
  bf16*  T5   = (bf16*)carve(p, SZ_PAD*2);
  bf16*  T6   = (bf16*)carve(p, SZ_PAD*2);
  bf16*  TA1  = (bf16*)carve(p, SZ_PAD*2);            // cur / new_outs pair
  bf16*  TA2  = (bf16*)carve(p, SZ_PAD*2);
  bf16*  TF1  = (bf16*)carve(p, SZ_PAD*2);            // fo pair (row-tiled)
  bf16*  TF2  = (bf16*)carve(p, SZ_PAD*2);
  bf16*  TT1  = (bf16*)carve(p, SZ_PAD*2);            // fo^T pair (from sk5)
  bf16*  TT2  = (bf16*)carve(p, SZ_PAD*2);
  bf16*  ADJB = (bf16*)carve(p, SZ_BNN*2);            // adj bf16 tiled (const)
  bf16*  Wh_all = (bf16*)carve(p, (size_t)21*HP*HP*2);   // +1 slack slot
  bf16*  Wl_all = (bf16*)carve(p, (size_t)21*HP*HP*2);
  float* cpm     = (float*)carve(p, (size_t)8*BN*4);  // col-stat partials
  float* cps     = (float*)carve(p, (size_t)8*BN*4);
  float* denom   = (float*)carve(p, BN*4);
  float* maskf   = (float*)carve(p, BN*4);
  float* maskadd = (float*)carve(p, BN*4);
  float* cmaxv   = (float*)carve(p, BN*4);
  float* csumv   = (float*)carve(p, BN*4);

  float* sc2 = out_outs;          // fp32 scratch; final sk6 overwrites in iter 2
  bf16* attnP = Rb;
  bf16* Ph    = Rb;
  bf16* Pl    = Rb + SZ_BNN;
  bf16* PcH   = Rc;
  bf16* PcL   = Rc + SZ_BNN;

  const size_t sNT = (size_t)Nd*HP;     // batch stride (tiled), 1024*224
  const size_t sT  = (size_t)HP*Nd;     // batch stride (tiled), 224*1024
  const size_t sNN = (size_t)Nd*Nd;     // batch stride, 1024*1024

  #define W_GCN 0
  #define W_MUT 1
  #define W_Q(i) (2 + (i))
  #define W_K(i) (5 + (i))
  #define W_V(i) (8 + (i))
  #define W_AO(i) (11 + (i))
  #define W_IW(i) (14 + (i))
  #define W_OW(i) (17 + (i))
  #define WH(s) (Wh_all + (size_t)(s)*HP*HP)
  #define WL(s) (Wl_all + (size_t)(s)*HP*HP)

  dim3 blk256(256);
  dim3 gPad((unsigned)((SZ_PAD+255)/256));
  dim3 gPadT(32, 7, Bd), bT(32, 8);
  dim3 gWall((HP*HP+255)/256, 20);
  dim3 gCvt(32, 128, Bd);
  dim3 gBNH((unsigned)((SZ_BNH+255)/256));
  dim3 gSm(4, 128, 1);       // small GEMM: 16x64/wave (RI=1), 8192 rows, K=HP
  dim3 gQKV(4, 128, 3);      // merged Q/K/V
  dim3 gNT(16, 8, Bd);       // scores/logits: 32x64/wave (RI=2), K=HP
  dim3 gSK(32, 4, Bd);       // split-K=4 mixes: 32-row blocks
  const float inv_sqrt_h = 0.07071067811865475f;  // 1/sqrt(200)
  const size_t Z = 0;
  float* FN = nullptr;
  bf16*  BN_ = nullptr;

  k_prep_masks<<<(BN+255)/256, blk256, 0, stream>>>(textmask, maskf, maskadd);
  k_prep_adj<<<BN, blk256, 0, stream>>>(adj1, adj2, out_adj, denom);
  k_copy2<<<gBNH, blk256, 0, stream>>>(text, cur, fo);
  c_w_split_all<<<gWall, blk256, 0, stream>>>(gcn_w, mut_w, qw, kw, vw, aow, iw, ow,
                                              Wh_all, Wl_all);
  c_pad_split<<<gPad, blk256, 0, stream>>>(text, TA1, TA2);   // BERT-in pair (iter 0)
  c_pad_split<<<gPad, blk256, 0, stream>>>(text, TF1, TF2);   // fo pair (iter 0)
  c_cvt1024_t<<<gCvt, blk256, 0, stream>>>(out_adj, ADJB);    // adj bf16 (const)

  for (int i = 0; i < 3; i++){
    const float *qbi = qb + i*Hd;
    const float *kbi = kb + i*Hd;
    const float *vbi = vb + i*Hd;
    const float *aobi= aob+ i*Hd;
    const float *g1i = g1 + i*Hd,    *b1i = b1 + i*Hd;
    const float *ibi = ib + i*Hd;
    const float *obi = ob + i*Hd;
    const float *g2i = g2 + i*Hd,    *b2i = b2 + i*Hd;

    // ================= BERT layer =================
    k_qkv<<<gQKV, blk256, 0, stream>>>(TA1,TA2, WH(W_Q(i)),WL(W_Q(i)),
              T3,T4, T5,T6, T1,T2, qbi,kbi,vbi);                            // Q,K pairs + V^T pair
    k_mfma3<3,3,2,HP><<<gNT, blk256, 0, stream>>>(T3,T4,T5,T6, S,BN_,BN_,
              nullptr, maskadd,nullptr, sNT,sNT, inv_sqrt_h, FN,FN);        // scores
    k_rowsoftmax<0><<<BN, blk256, 0, stream>>>(S, attnP, BN_, FN,FN, BN_,BN_);
    k_mfma3sk<8,2,Nd><<<gSK, blk256, 0, stream>>>(attnP,BN_,T1,T2,
              FN,T3,T4, FN,FN,FN, sNN,sT, BN_,BN_);                         // ctx pair
    k_mfma3<0,3,1,HP><<<gSm, blk256, 0, stream>>>(T3,T4,WH(W_AO(i)),WL(W_AO(i)),
              sc1,BN_,BN_, aobi, FN,FN, Z,Z, 0.f, FN,FN);                   // ao_out fp32
    k_add_ln<<<BN, blk256, 0, stream>>>(sc1, cur, g1i, b1i, sc2, T1, T2);   // ln1 + pair
    k_mfma3<10,3,1,HP><<<gSm, blk256, 0, stream>>>(T1,T2,WH(W_IW(i)),WL(W_IW(i)),
              FN,T3,T4, ibi, FN,FN, Z,Z, 0.f, FN,FN);                       // gelu pair
    k_mfma3<0,3,1,HP><<<gSm, blk256, 0, stream>>>(T3,T4,WH(W_OW(i)),WL(W_OW(i)),
              cur,BN_,BN_, obi, FN,FN, Z,Z, 0.f, FN,FN);                    // ow_out fp32
    k_add_ln<<<BN, blk256, 0, stream>>>(cur, sc2, g2i, b2i, cur, TA1, TA2); // ln2 + pair

    // ================= GCN on fo =================
    k_mfma3<9,3,1,HP><<<gSm, blk256, 0, stream>>>(TF1,TF2,WH(W_GCN),WL(W_GCN),
              FN,T1,T2, nullptr, FN,FN, Z,Z, 0.f, FN,FN);                   // teout^T pair
    k_mfma3sk<5,2,Nd><<<gSK, blk256, 0, stream>>>(ADJB,BN_,T1,T2,
              fo,TF1,TF2, denom,FN,FN, sNN,sT, TT1,TT2);                    // fo update + pair + fo^T

    // ================= self-alignment =================
    k_mfma3<2,3,1,HP><<<gSm, blk256, 0, stream>>>(TA1,TA2,WH(W_MUT),WL(W_MUT),
              FN,T5,T6, nullptr, FN,FN, Z,Z, 0.f, FN,FN);                   // mm pair
    k_mfma3<4,3,2,HP><<<gNT, blk256, 0, stream>>>(T5,T6,TF1,TF2, S,BN_,BN_,
              nullptr, nullptr,maskf, sNT,sNT, 0.f, cpm,cps);               // logits + col partials
    k_colcomb<<<BN/256, blk256, 0, stream>>>(cpm, cps, cmaxv, csumv);
    k_rowsoftmax<2><<<BN, blk256, 0, stream>>>(S, Ph, Pl, cmaxv, csumv, PcH, PcL);
    c_padT_split<<<gPadT, bT, 0, stream>>>(cur, T3, T4);                    // outs^T (POST-BERT cur)
    k_mfma3sk<6,3,Nd><<<gSK, blk256, 0, stream>>>(Ph,Pl,TT1,TT2,
              (i==2)?out_outs:sc1, TA1,TA2, FN,maskf,cur, sNN,sT, BN_,BN_); // new_outs + pair
    k_mfma3sk<7,3,Nd><<<gSK, blk256, 0, stream>>>(PcH,PcL,T3,T4,
              fo,TF1,TF2, FN,maskf,FN, sNN,sT, BN_,BN_);                    // fo update + pair

    float* t = cur; cur = sc1; sc1 = t;          // outs = new_outs (fp32 chain)
  }
}

// Round 9
// 1143.371 us; speedup vs baseline: 1.1529x; 1.1529x over previous
//
#include <hip/hip_runtime.h>
#include <hip/hip_bf16.h>
#include <math.h>

// Problem constants
#define Bd 8
#define Nd 1024
#define Hd 200
#define HP 224                      // Hd padded to multiple of 32
#define BN (Bd*Nd)                  // 8192
#define SZ_BNH ((size_t)BN*Hd)      // 1,638,400
#define SZ_BNN ((size_t)BN*Nd)      // 8,388,608
#define SZ_PAD ((size_t)BN*HP)      // 1,835,008

typedef __hip_bfloat16 bf16;
typedef __attribute__((ext_vector_type(8))) short bf16x8;   // 8 bf16 = 4 VGPRs (A/B frag)
typedef __attribute__((ext_vector_type(4))) float f32x4;    // C/D frag
typedef __attribute__((ext_vector_type(4))) short s16x4;    // 4 bf16 = 8B store

__device__ __forceinline__ float bf2f(bf16 v){ return __bfloat162float(v); }
__device__ __forceinline__ bf16 f2bf(float v){ return __float2bfloat16(v); }
__device__ __forceinline__ short bfb(float v){ bf16 h = f2bf(v); return *(short*)&h; }
__device__ __forceinline__ short lowb(float v){
  bf16 h = f2bf(v); bf16 l = f2bf(v - bf2f(h)); return *(short*)&l;
}

#define MFMA16(a,b,c) __builtin_amdgcn_mfma_f32_16x16x32_bf16((a),(b),(c),0,0,0)

// Fragment-native tiled layout. Element (row, k) of a [R][KP] matrix lives at:
//   (row>>4)*16*KP + (k>>5)*512 + ((k>>3)&3)*128 + (row&15)*8 + (k&7)
__device__ __forceinline__ size_t tidx1024(int row, int k){
  return (size_t)(row>>4)*16384 + (size_t)((k>>5))*512
       + (size_t)(((k>>3)&3))*128 + (size_t)(row&15)*8 + (k&7);
}
__device__ __forceinline__ size_t tidxHP(int row, int k){
  return (size_t)(row>>4)*3584 + (size_t)((k>>5))*512
       + (size_t)(((k>>3)&3))*128 + (size_t)(row&15)*8 + (k&7);
}

// ============================ prep (fp32) ============================
__global__ void k_prep_masks(const float* __restrict__ tm, float* __restrict__ maskf,
                             float* __restrict__ maskadd){
  int i = blockIdx.x*256 + threadIdx.x;
  if (i < BN){ float m = tm[i]; maskf[i] = m; maskadd[i] = (1.f - m) * -10000.f; }
}

__global__ void k_prep_adj(const float* __restrict__ a1, const float* __restrict__ a2,
                           float* __restrict__ adj_out, float* __restrict__ denom){
  int r = blockIdx.x;
  const size_t base = (size_t)r * Nd;
  int t = threadIdx.x;
  float s = 0.f;
  for (int m = t; m < Nd; m += 256){
    float a = a1[base+m] + a2[base+m];
    a = a >= 1.f ? 1.f : a;
    adj_out[base+m] = a;
    s += a;
  }
  __shared__ float red[256];
  red[t] = s; __syncthreads();
  for (int st = 128; st > 0; st >>= 1){ if (t < st) red[t] += red[t+st]; __syncthreads(); }
  if (t == 0) denom[r] = red[0] + 1e-07f;
}

__global__ void k_copy2(const float* __restrict__ x, float* __restrict__ o1,
                        float* __restrict__ o2){
  size_t i = (size_t)blockIdx.x*256 + threadIdx.x;
  if (i < SZ_BNH){ float v = x[i]; o1[i] = v; o2[i] = v; }
}

// ============================ split conversions ============================
__global__ void c_pad_split(const float* __restrict__ X, bf16* __restrict__ Oh,
                            bf16* __restrict__ Ol){
  size_t o = (size_t)blockIdx.x*256 + threadIdx.x;
  if (o >= SZ_PAD) return;
  int oi = (int)o;
  int panel = oi / 3584;             // 16*HP
  int rem   = oi % 3584;
  int kt  = rem >> 9;
  int kg  = (rem >> 7) & 3;
  int r16 = (rem >> 3) & 15;
  int ke  = rem & 7;
  int row = panel*16 + r16;
  int k   = kt*32 + kg*8 + ke;
  float v = (k < Hd) ? X[(size_t)row*Hd + k] : 0.f;
  bf16 h = f2bf(v);
  Oh[o] = h; Ol[o] = f2bf(v - bf2f(h));
}

// Transpose-pad-split writing the TILED-1024 layout (row = d, k = m).
__global__ void c_padT_split(const float* __restrict__ X, bf16* __restrict__ Oh,
                             bf16* __restrict__ Ol){
  __shared__ float t[32][33];
  int b = blockIdx.z, m0 = blockIdx.x*32, d0 = blockIdx.y*32;
  int tx = threadIdx.x, ty = threadIdx.y;          // block (32,8)
  for (int i = ty; i < 32; i += 8){
    int d = d0 + tx;
    t[i][tx] = (d < Hd) ? X[((size_t)b*Nd + m0+i)*Hd + d] : 0.f;
  }
  __syncthreads();
  for (int i = ty; i < 32; i += 8){
    int row = d0 + i, kk = m0 + tx;
    size_t idx = (size_t)b*229376 + tidx1024(row, kk);
    float v = t[tx][i];
    bf16 h = f2bf(v);
    Oh[idx] = h; Ol[idx] = f2bf(v - bf2f(h));
  }
}

// Batched weight split -> TILED layout.
// mi: 0=gcn 1=mut 2..4=qw 5..7=kw 8..10=vw 11..13=aow 14..16=iw 17..19=ow
__global__ void c_w_split_all(const float* __restrict__ g, const float* __restrict__ m,
                              const float* __restrict__ q, const float* __restrict__ k,
                              const float* __restrict__ v, const float* __restrict__ ao,
                              const float* __restrict__ iw, const float* __restrict__ ow,
                              bf16* __restrict__ Oh, bf16* __restrict__ Ol){
  int mi = blockIdx.y;
  const float* W;
  if (mi == 0) W = g;
  else if (mi == 1) W = m;
  else {
    int gi = (mi-2)/3, si = (mi-2)%3;
    const float* bs[6] = {q, k, v, ao, iw, ow};
    W = bs[gi] + (size_t)si*Hd*Hd;
  }
  int o = blockIdx.x*256 + threadIdx.x;
  if (o >= HP*HP) return;
  int panel = o / 3584;
  int rem   = o % 3584;
  int kt  = rem >> 9;
  int kg  = (rem >> 7) & 3;
  int r16 = (rem >> 3) & 15;
  int ke  = rem & 7;
  int n   = panel*16 + r16;          // output col (B-matrix row)
  int kk  = kt*32 + kg*8 + ke;
  float val = (n < Hd && kk < Hd) ? W[kk*Hd + n] : 0.f;
  bf16 h = f2bf(val);
  Oh[(size_t)mi*HP*HP + o] = h; Ol[(size_t)mi*HP*HP + o] = f2bf(val - bf2f(h));
}

// adj -> bf16 tiled-1024 (once; adj constant across iterations).
__global__ void c_cvt1024_t(const float* __restrict__ X, bf16* __restrict__ O){
  int b = blockIdx.z, kg = blockIdx.x, rg = blockIdx.y;
  int r = threadIdx.x >> 5, kl = threadIdx.x & 31;
  int row = rg*8 + r, k = kg*32 + kl;
  float v = X[(size_t)b*1048576 + (size_t)row*1024 + k];
  O[(size_t)b*1048576 + tidx1024(row, k)] = f2bf(v);
}

// ============================ fused row softmax ============================
// Hybrid: register-resident float4 read + 1-exp p_row (Round-6 VALU win), but
// p_col^T pass uses LDS row staging with CONSECUTIVE-m lane mapping (Round-5
// store coalescing: lanes write consecutive m -> ~8 lines/wave-instr, vs 64
// with the stride-4 interleave that made Round 6 store-bound).
// SPLIT=0: single-bf16 p_row only. SPLIT=2: p_row pair + p_col^T pair.
template<int SPLIT>
__global__ __launch_bounds__(256)
void k_rowsoftmax(const float* __restrict__ S, bf16* __restrict__ Ph,
                  bf16* __restrict__ Pl, const float* __restrict__ cmax,
                  const float* __restrict__ csum, bf16* __restrict__ PcH,
                  bf16* __restrict__ PcL){
  __shared__ float red[256];
  __shared__ float row[(SPLIT == 2) ? Nd : 4];
  size_t bid = blockIdx.x;
  size_t r = ((bid & 7) << 10) + (bid >> 3);     // batch = bid&7, slot = bid>>3
  int t = threadIdx.x;
  const f32x4 v4 = *(const f32x4*)(S + r*Nd + t*4);
  if (SPLIT == 2) *(f32x4*)(row + t*4) = v4;
  float mx = fmaxf(fmaxf(v4[0], v4[1]), fmaxf(v4[2], v4[3]));
  red[t] = mx; __syncthreads();
  for (int s = 128; s > 0; s >>= 1){ if (t < s) red[t] = fmaxf(red[t], red[t+s]); __syncthreads(); }
  mx = red[0]; __syncthreads();
  float e0 = __expf(v4[0] - mx), e1 = __expf(v4[1] - mx);
  float e2 = __expf(v4[2] - mx), e3 = __expf(v4[3] - mx);
  red[t] = (e0 + e1) + (e2 + e3); __syncthreads();
  for (int s = 128; s > 0; s >>= 1){ if (t < s) red[t] += red[t+s]; __syncthreads(); }
  float inv = 1.f / red[0];
  size_t obase = ((r >> 10) << 20) + (size_t)(((int)(r & 1023)) >> 4)*16384
               + (size_t)((int)r & 15)*8;
  {
    int i = t*4;
    size_t idx = obase + (size_t)(i>>5)*512 + (size_t)((i>>3)&3)*128 + (i&7);
    float p0 = e0*inv, p1 = e1*inv, p2 = e2*inv, p3 = e3*inv;
    s16x4 hv = { bfb(p0), bfb(p1), bfb(p2), bfb(p3) };
    *(s16x4*)(Ph + idx) = hv;
    if (SPLIT == 2){
      s16x4 lv = { lowb(p0), lowb(p1), lowb(p2), lowb(p3) };
      *(s16x4*)(Pl + idx) = lv;
    }
  }
  if (SPLIT == 2){
    int bq = (int)(r >> 10);
    int n  = (int)(r & 1023);
    size_t nb = (size_t)bq * 1048576;
    #pragma unroll
    for (int k = 0; k < 4; k++){
      int m = t + 256*k;                       // consecutive lanes -> consecutive m
      float ci = 1.f / csum[bq*Nd + m];
      float p = __expf(row[m] - cmax[bq*Nd + m]) * ci;
      bf16 h = f2bf(p);
      size_t idx = nb + tidx1024(m, n);
      PcH[idx] = h; PcL[idx] = f2bf(p - bf2f(h));
    }
  }
}

// Combine 8 per-rowblock column partials into final column stats.
__global__ void k_colcomb(const float* __restrict__ cpm, const float* __restrict__ cps,
                          float* __restrict__ cmax, float* __restrict__ csum){
  int i = blockIdx.x*256 + threadIdx.x;    // global col b*1024+m
  float M = cpm[i], S = cps[i];
  #pragma unroll
  for (int y = 1; y < 8; y++){
    float m2 = cpm[(size_t)y*BN + i], s2 = cps[(size_t)y*BN + i];
    float Mn = fmaxf(M, m2);
    S = S*__expf(M - Mn) + s2*__expf(m2 - Mn);
    M = Mn;
  }
  cmax[i] = M; csum[i] = S;
}

// ============================ residual + layernorm (+ optional pair out) =========
__global__ void k_add_ln(const float* __restrict__ X, const float* __restrict__ R,
                         const float* __restrict__ g, const float* __restrict__ bb,
                         float* __restrict__ Y, bf16* __restrict__ Ph,
                         bf16* __restrict__ Pl){
  int r = blockIdx.x, t = threadIdx.x;
  __shared__ float red[256];
  bool act = t < Hd;
  float v = 0.f;
  if (act) v = X[(size_t)r*Hd + t] + R[(size_t)r*Hd + t];
  red[t] = act ? v : 0.f; __syncthreads();
  for (int s = 128; s > 0; s >>= 1){ if (t < s) red[t] += red[t+s]; __syncthreads(); }
  float mu = red[0] * (1.f/Hd); __syncthreads();
  float d = act ? (v - mu) : 0.f;
  red[t] = d*d; __syncthreads();
  for (int s = 128; s > 0; s >>= 1){ if (t < s) red[t] += red[t+s]; __syncthreads(); }
  float var = red[0] * (1.f/Hd);
  float o = 0.f;
  if (act){
    float rs = 1.f / sqrtf(var + 1e-20f);
    o = (v - mu) * rs * g[t] + bb[t];
    Y[(size_t)r*Hd + t] = o;
  }
  if (Ph && t < HP){
    bf16 h = f2bf(o);
    size_t idx = tidxHP(r, t);
    Ph[idx] = h; Pl[idx] = f2bf(o - bf2f(h));
  }
}

// ============================ merged Q/K/V GEMM ============================
// blockIdx.z = slice: 0=Q (pair->QH/QL), 1=K (pair->KH/KL), 2=V (transposed pair
// ->VH/VL via LDS). Weight slot base Wh0/Wl0 = Q slot; slice stride 3 slots.
__global__ __launch_bounds__(256)
void k_qkv(const bf16* __restrict__ Ah, const bf16* __restrict__ Al,
           const bf16* __restrict__ Wh0, const bf16* __restrict__ Wl0,
           bf16* __restrict__ QH, bf16* __restrict__ QL,
           bf16* __restrict__ KH, bf16* __restrict__ KL,
           bf16* __restrict__ VH, bf16* __restrict__ VL,
           const float* __restrict__ qb, const float* __restrict__ kb,
           const float* __restrict__ vb)
{
  constexpr int KP = HP;
  constexpr int STEPS = KP/32;
  int slice = blockIdx.z;
  int wave = threadIdx.x >> 6, lane = threadIdx.x & 63;
  int r0 = (blockIdx.y*4 + wave)*16;
  int c0 = blockIdx.x*64;
  int lm = lane & 15, lq = lane >> 4;
  const size_t PST = (size_t)16*KP;
  const size_t aT = (size_t)(r0>>4)*PST + (size_t)lane*8;
  const size_t bT = (size_t)slice*3*HP*HP + (size_t)(c0>>4)*PST + (size_t)lane*8;

  f32x4 acc[4] = {};
  bf16x8 pah[2], pal[2], pbh[2][4], pbl[2][4];
  pah[0] = *(const bf16x8*)(Ah + aT);
  pal[0] = *(const bf16x8*)(Al + aT);
  #pragma unroll
  for (int j = 0; j < 4; j++){
    pbh[0][j] = *(const bf16x8*)(Wh0 + bT + (size_t)j*PST);
    pbl[0][j] = *(const bf16x8*)(Wl0 + bT + (size_t)j*PST);
  }
  #pragma unroll
  for (int ki = 0; ki < STEPS; ki++){
    const int cb = ki & 1, nb = cb ^ 1;
    if (ki + 1 < STEPS){
      const size_t kn = (size_t)(ki+1)*512;
      pah[nb] = *(const bf16x8*)(Ah + aT + kn);
      pal[nb] = *(const bf16x8*)(Al + aT + kn);
      #pragma unroll
      for (int j = 0; j < 4; j++){
        pbh[nb][j] = *(const bf16x8*)(Wh0 + bT + (size_t)j*PST + kn);
        pbl[nb][j] = *(const bf16x8*)(Wl0 + bT + (size_t)j*PST + kn);
      }
    }
    #pragma unroll
    for (int j = 0; j < 4; j++) acc[j] = MFMA16(pah[cb], pbh[cb][j], acc[j]);
    #pragma unroll
    for (int j = 0; j < 4; j++) acc[j] = MFMA16(pah[cb], pbl[cb][j], acc[j]);
    #pragma unroll
    for (int j = 0; j < 4; j++) acc[j] = MFMA16(pal[cb], pbh[cb][j], acc[j]);
  }

  const float* bias = (slice == 0) ? qb : (slice == 1) ? kb : vb;
  if (slice < 2){
    bf16* Oh = (slice == 0) ? QH : KH;
    bf16* Ol = (slice == 0) ? QL : KL;
    #pragma unroll
    for (int j = 0; j < 4; j++){
      int col = c0 + j*16 + lm;
      if (col >= HP) continue;
      #pragma unroll
      for (int r = 0; r < 4; r++){
        int row = r0 + lq*4 + r;
        float o = (col < Hd) ? acc[j][r] + bias[col] : 0.f;
        bf16 h = f2bf(o);
        size_t idx = tidxHP(row, col);
        Oh[idx] = h; Ol[idx] = f2bf(o - bf2f(h));
      }
    }
  } else {
    __shared__ float tl[64][65];
    #pragma unroll
    for (int j = 0; j < 4; j++)
      #pragma unroll
      for (int r = 0; r < 4; r++)
        tl[wave*16 + lq*4 + r][j*16 + lm] = acc[j][r];
    __syncthreads();
    int b2 = (int)((blockIdx.y*64) >> 10);
    int m0 = (int)((blockIdx.y*64) & 1023);
    #pragma unroll
    for (int e = threadIdx.x; e < 4096; e += 256){
      int pan = e >> 10, rem = e & 1023;
      int r16 = (rem >> 3) & 15;
      int d = c0 + pan*16 + r16;
      if (d >= HP) continue;
      int kg = (rem >> 7) & 3;
      int k_loc = (rem >> 9)*32 + kg*8 + (rem & 7);
      float val = 0.f;
      if (d < Hd) val = tl[k_loc][pan*16 + r16] + bias[d];
      bf16 h = f2bf(val);
      size_t idx = (size_t)b2*229376 + (size_t)(d>>4)*16384
                 + (size_t)((m0 + k_loc)>>5)*512 + (size_t)kg*128
                 + (size_t)r16*8 + (rem & 7);
      VH[idx] = h; VL[idx] = f2bf(val - bf2f(h));
    }
  }
}

// ============================ split-precision MFMA GEMM (no split-K) ============
// EPI: 0 fp32 Y=acc+bias   2 split-bf16 row-tiled pair out (+bias)
//      3 S=acc*scale+maskadd[col]   4 S=acc+pairmask (+ column-stats partials)
//      9 TRANSPOSED tiled pair out (+bias) via LDS   10 gelu -> row-tiled pair
template<int EPI, int TERMS, int RI, int KP>
__global__ __launch_bounds__(256)
void k_mfma3(const bf16* __restrict__ Ah, const bf16* __restrict__ Al,
             const bf16* __restrict__ Bh, const bf16* __restrict__ Bl,
             float* __restrict__ Y, bf16* __restrict__ Ybh, bf16* __restrict__ Ybl,
             const float* __restrict__ bias, const float* __restrict__ e0,
             const float* __restrict__ e1,
             size_t sAb, size_t sBb, float scale,
             float* __restrict__ cpm, float* __restrict__ cps)
{
  int b = blockIdx.z;
  int wave = threadIdx.x >> 6, lane = threadIdx.x & 63;
  int r0 = (blockIdx.y*4 + wave)*(RI*16);
  int c0 = blockIdx.x*64;
  int lm = lane & 15, lq = lane >> 4;
  const size_t PST = (size_t)16*KP;     // panel stride (elements)
  const size_t aT = (size_t)b*sAb + (size_t)(r0>>4)*PST + (size_t)lane*8;
  const size_t bT = (size_t)b*sBb + (size_t)(c0>>4)*PST + (size_t)lane*8;
  constexpr int STEPS = KP/32;

  f32x4 acc[RI][4] = {};
  bf16x8 pah[2][RI], pal[2][RI], pbh[2][4], pbl[2][4];
  {
    #pragma unroll
    for (int i = 0; i < RI; i++) pah[0][i] = *(const bf16x8*)(Ah + aT + (size_t)i*PST);
    #pragma unroll
    for (int j = 0; j < 4; j++){
      pbh[0][j] = *(const bf16x8*)(Bh + bT + (size_t)j*PST);
      pbl[0][j] = *(const bf16x8*)(Bl + bT + (size_t)j*PST);
    }
    if (TERMS >= 3){
      #pragma unroll
      for (int i = 0; i < RI; i++) pal[0][i] = *(const bf16x8*)(Al + aT + (size_t)i*PST);
    }
  }

  #pragma unroll
  for (int ki = 0; ki < STEPS; ki++){
    const int cb = ki & 1, nb = cb ^ 1;
    if (ki + 1 < STEPS){
      const size_t kn = (size_t)(ki+1)*512;
      #pragma unroll
      for (int i = 0; i < RI; i++) pah[nb][i] = *(const bf16x8*)(Ah + aT + (size_t)i*PST + kn);
      #pragma unroll
      for (int j = 0; j < 4; j++){
        pbh[nb][j] = *(const bf16x8*)(Bh + bT + (size_t)j*PST + kn);
        pbl[nb][j] = *(const bf16x8*)(Bl + bT + (size_t)j*PST + kn);
      }
      if (TERMS >= 3){
        #pragma unroll
        for (int i = 0; i < RI; i++) pal[nb][i] = *(const bf16x8*)(Al + aT + (size_t)i*PST + kn);
      }
    }
    #pragma unroll
    for (int i = 0; i < RI; i++)
      #pragma unroll
      for (int j = 0; j < 4; j++) acc[i][j] = MFMA16(pah[cb][i], pbh[cb][j], acc[i][j]);
    #pragma unroll
    for (int i = 0; i < RI; i++)
      #pragma unroll
      for (int j = 0; j < 4; j++) acc[i][j] = MFMA16(pah[cb][i], pbl[cb][j], acc[i][j]);
    if (TERMS >= 3){
      #pragma unroll
      for (int i = 0; i < RI; i++)
        #pragma unroll
        for (int j = 0; j < 4; j++) acc[i][j] = MFMA16(pal[cb][i], pbh[cb][j], acc[i][j]);
    }
  }

  if constexpr (EPI == 9){
    __shared__ float tl[64][65];
    #pragma unroll
    for (int j = 0; j < 4; j++)
      #pragma unroll
      for (int r = 0; r < 4; r++)
        tl[wave*16 + lq*4 + r][j*16 + lm] = acc[0][j][r];
    __syncthreads();
    int b2 = (int)((blockIdx.y*64) >> 10);
    int m0 = (int)((blockIdx.y*64) & 1023);
    #pragma unroll
    for (int e = threadIdx.x; e < 4096; e += 256){
      int pan = e >> 10, rem = e & 1023;
      int r16 = (rem >> 3) & 15;
      int d = c0 + pan*16 + r16;
      if (d >= HP) continue;
      int kg = (rem >> 7) & 3;
      int k_loc = (rem >> 9)*32 + kg*8 + (rem & 7);
      float val = 0.f;
      if (d < Hd) val = tl[k_loc][pan*16 + r16] + (bias ? bias[d] : 0.f);
      bf16 h = f2bf(val);
      size_t idx = (size_t)b2*229376 + (size_t)(d>>4)*16384
                 + (size_t)((m0 + k_loc)>>5)*512 + (size_t)kg*128
                 + (size_t)r16*8 + (rem & 7);
      Ybh[idx] = h; Ybl[idx] = f2bf(val - bf2f(h));
    }
  } else if constexpr (EPI == 4){
    // logits + per-block column-softmax partials (max, sum-exp over 128 rows)
    float er[RI][4];
    #pragma unroll
    for (int i = 0; i < RI; i++)
      #pragma unroll
      for (int r = 0; r < 4; r++)
        er[i][r] = e1[b*Nd + r0 + i*16 + lq*4 + r];
    float cm[4], cs[4];
    #pragma unroll
    for (int j = 0; j < 4; j++){
      int col = c0 + j*16 + lm;
      float e1c = e1[b*Nd + col];
      float wv[RI][4];
      float mloc = -3.4e38f;
      #pragma unroll
      for (int i = 0; i < RI; i++){
        #pragma unroll
        for (int r = 0; r < 4; r++){
          int row = r0 + i*16 + lq*4 + r;
          float w = acc[i][j][r] + (1.f - er[i][r]*e1c)*(-10000.f);
          Y[((size_t)b*Nd + row)*Nd + col] = w;
          wv[i][r] = w;
          mloc = fmaxf(mloc, w);
        }
      }
      float sloc = 0.f;
      #pragma unroll
      for (int i = 0; i < RI; i++)
        #pragma unroll
        for (int r = 0; r < 4; r++) sloc += __expf(wv[i][r] - mloc);
      cm[j] = mloc; cs[j] = sloc;
    }
    #pragma unroll
    for (int j = 0; j < 4; j++){
      float m = cm[j], s = cs[j];
      #pragma unroll
      for (int off = 16; off <= 32; off <<= 1){
        float m2 = __shfl_xor(m, off), s2 = __shfl_xor(s, off);
        float M = fmaxf(m, m2);
        s = s*__expf(m - M) + s2*__expf(m2 - M);
        m = M;
      }
      cm[j] = m; cs[j] = s;
    }
    __shared__ float pmx[4][4][16], psm[4][4][16];
    if (lq == 0){
      #pragma unroll
      for (int j = 0; j < 4; j++){ pmx[wave][j][lm] = cm[j]; psm[wave][j][lm] = cs[j]; }
    }
    __syncthreads();
    if (threadIdx.x < 64){
      int t = threadIdx.x;             // col-in-block = t (j=t>>4, lm=t&15)
      int jj = t >> 4, cc = t & 15;
      float M = pmx[0][jj][cc], S = psm[0][jj][cc];
      #pragma unroll
      for (int w = 1; w < 4; w++){
        float m2 = pmx[w][jj][cc], s2 = psm[w][jj][cc];
        float Mn = fmaxf(M, m2);
        S = S*__expf(M - Mn) + s2*__expf(m2 - Mn);
        M = Mn;
      }
      size_t pi = (size_t)blockIdx.y*BN + (size_t)b*Nd + c0 + t;
      cpm[pi] = M; cps[pi] = S;
    }
  } else {
    #pragma unroll
    for (int i = 0; i < RI; i++){
      #pragma unroll
      for (int j = 0; j < 4; j++){
        int col = c0 + j*16 + lm;
        int rbase = r0 + i*16 + lq*4;
        #pragma unroll
        for (int r = 0; r < 4; r++){
          int row = rbase + r;
          size_t rowg = (size_t)b*Nd + row;
          float v = acc[i][j][r];
          if (EPI == 0){
            if (col < Hd){
              v += bias ? bias[col] : 0.f;
              Y[rowg*Hd + col] = v;
            }
          } else if (EPI == 2){
            if (col < HP){
              float o = (col < Hd) ? v + (bias ? bias[col] : 0.f) : 0.f;
              bf16 h = f2bf(o);
              size_t idx = tidxHP((int)rowg, col);
              Ybh[idx] = h;
              Ybl[idx] = f2bf(o - bf2f(h));
            }
          } else if (EPI == 3){
            Y[rowg*Nd + col] = v*scale + e0[b*Nd + col];
          } else if (EPI == 10){
            if (col < HP){
              float o = 0.f;
              if (col < Hd){
                float vv = v + (bias ? bias[col] : 0.f);
                o = 0.5f*vv*(1.f + erff(vv*0.7071067811865476f));
              }
              bf16 h = f2bf(o);
              size_t idx = tidxHP((int)rowg, col);
              Ybh[idx] = h;
              Ybl[idx] = f2bf(o - bf2f(h));
            }
          }
        }
      }
    }
  }
}

// ============================ split-K=4 MFMA GEMM (K=1024 mixes) ================
// EPI: 5 Y+=relu(acc/denom[row]) + pair   6 Y=acc*maskf[row]+R + pair
//      7 Y=acc*maskf[row]+Y + pair        8 pair only (ctx)
// Optional TbH/TbL: ALSO write the transposed tiled-1024 pair (d=col, k=row).
template<int EPI, int TERMS, int KP>
__global__ __launch_bounds__(256)
void k_mfma3sk(const bf16* __restrict__ Ah, const bf16* __restrict__ Al,
               const bf16* __restrict__ Bh, const bf16* __restrict__ Bl,
               float* __restrict__ Y, bf16* __restrict__ Ybh, bf16* __restrict__ Ybl,
               const float* __restrict__ e0, const float* __restrict__ e1,
               const float* __restrict__ R,
               size_t sAb, size_t sBb,
               bf16* __restrict__ TbH, bf16* __restrict__ TbL)
{
  __shared__ float red[4][64][33];
  int b = blockIdx.z;
  int wave = threadIdx.x >> 6, lane = threadIdx.x & 63;
  int r0 = blockIdx.x*32;
  int c0 = blockIdx.y*64;
  int lm = lane & 15, lq = lane >> 4;
  const size_t aT = (size_t)b*sAb + (size_t)(r0>>4)*((size_t)16*KP) + (size_t)lane*8;
  const size_t bT = (size_t)b*sBb + (size_t)(c0>>4)*((size_t)16*KP) + (size_t)lane*8;
  const int kt0 = wave*(KP>>7);
  constexpr int STEPS = KP/128;

  f32x4 acc[2][4] = {};
  bf16x8 pah[2][2], pal[2][2], pbh[2][4], pbl[2][4];
  {
    const size_t ko = (size_t)kt0*512;
    #pragma unroll
    for (int i = 0; i < 2; i++) pah[0][i] = *(const bf16x8*)(Ah + aT + (size_t)(i*16)*KP + ko);
    #pragma unroll
    for (int j = 0; j < 4; j++){
      pbh[0][j] = *(const bf16x8*)(Bh + bT + (size_t)(j*16)*KP + ko);
      pbl[0][j] = *(const bf16x8*)(Bl + bT + (size_t)(j*16)*KP + ko);
    }
    if (TERMS >= 3){
      #pragma unroll
      for (int i = 0; i < 2; i++) pal[0][i] = *(const bf16x8*)(Al + aT + (size_t)(i*16)*KP + ko);
    }
  }

  #pragma unroll
  for (int ki = 0; ki < STEPS; ki++){
    const int cb = ki & 1, nb = cb ^ 1;
    if (ki + 1 < STEPS){
      const size_t kn = (size_t)(kt0 + ki + 1)*512;
      #pragma unroll
      for (int i = 0; i < 2; i++) pah[nb][i] = *(const bf16x8*)(Ah + aT + (size_t)(i*16)*KP + kn);
      #pragma unroll
      for (int j = 0; j < 4; j++){
        pbh[nb][j] = *(const bf16x8*)(Bh + bT + (size_t)(j*16)*KP + kn);
        pbl[nb][j] = *(const bf16x8*)(Bl + bT + (size_t)(j*16)*KP + kn);
      }
      if (TERMS >= 3){
        #pragma unroll
        for (int i = 0; i < 2; i++) pal[nb][i] = *(const bf16x8*)(Al + aT + (size_t)(i*16)*KP + kn);
      }
    }
    #pragma unroll
    for (int i = 0; i < 2; i++)
      #pragma unroll
      for (int j = 0; j < 4; j++) acc[i][j] = MFMA16(pah[cb][i], pbh[cb][j], acc[i][j]);
    #pragma unroll
    for (int i = 0; i < 2; i++)
      #pragma unroll
      for (int j = 0; j < 4; j++) acc[i][j] = MFMA16(pah[cb][i], pbl[cb][j], acc[i][j]);
    if (TERMS >= 3){
      #pragma unroll
      for (int i = 0; i < 2; i++)
        #pragma unroll
        for (int j = 0; j < 4; j++) acc[i][j] = MFMA16(pal[cb][i], pbh[cb][j], acc[i][j]);
    }
  }

  #pragma unroll
  for (int i = 0; i < 2; i++)
    #pragma unroll
    for (int j = 0; j < 4; j++)
      #pragma unroll
      for (int r = 0; r < 4; r++)
        red[wave][lane][i*16 + j*4 + r] = acc[i][j][r];
  __syncthreads();

  int iw = wave >> 1, j0 = (wave & 1)*2;
  #pragma unroll
  for (int jj = 0; jj < 2; jj++){
    int j = j0 + jj;
    int col = c0 + j*16 + lm;
    #pragma unroll
    for (int r = 0; r < 4; r++){
      int f = iw*16 + j*4 + r;
      float v = red[0][lane][f] + red[1][lane][f] + red[2][lane][f] + red[3][lane][f];
      int row = r0 + iw*16 + lq*4 + r;
      size_t rowg = (size_t)b*Nd + row;
      if (col < HP){
        float nv = 0.f;
        if (EPI == 8){
          nv = (col < Hd) ? v : 0.f;
        } else if (EPI == 5){
          if (col < Hd){
            float u = v / e0[b*Nd+row]; u = u > 0.f ? u : 0.f;
            nv = Y[rowg*Hd + col] + u;
            Y[rowg*Hd + col] = nv;
          }
        } else if (EPI == 6){
          if (col < Hd){
            nv = v*e1[b*Nd+row] + R[rowg*Hd+col];
            Y[rowg*Hd + col] = nv;
          }
        } else if (EPI == 7){
          if (col < Hd){
            nv = v*e1[b*Nd+row] + Y[rowg*Hd+col];
            Y[rowg*Hd + col] = nv;
          }
        }
        bf16 h = f2bf(nv);
        bf16 lo = f2bf(nv - bf2f(h));
        size_t idx = tidxHP((int)rowg, col);
        Ybh[idx] = h; Ybl[idx] = lo;
        if (TbH != nullptr){
          size_t idx2 = (size_t)b*((size_t)HP*Nd) + tidx1024(col, row);
          TbH[idx2] = h; TbL[idx2] = lo;
        }
      }
    }
  }
}

// ============================ host launch ============================
static inline char* carve(char*& p, size_t bytes){
  char* r = p;
  p += (bytes + 511) & ~(size_t)511;
  return r;
}

extern "C" void kernel_launch(void* const* d_in, const int* in_sizes, int n_in,
                              void* d_out, int out_size, void* d_ws, size_t ws_size,
                              hipStream_t stream){
  (void)in_sizes; (void)n_in; (void)out_size; (void)ws_size;
  const float* text     = (const float*)d_in[0];
  const float* adj1     = (const float*)d_in[1];
  const float* adj2     = (const float*)d_in[2];
  const float* textmask = (const float*)d_in[5];
  const float* gcn_w    = (const float*)d_in[6];
  const float* mut_w    = (const float*)d_in[7];
  const float* qw = (const float*)d_in[8],  *qb = (const float*)d_in[9];
  const float* kw = (const float*)d_in[10], *kb = (const float*)d_in[11];
  const float* vw = (const float*)d_in[12], *vb = (const float*)d_in[13];
  const float* aow= (const float*)d_in[14], *aob= (const float*)d_in[15];
  const float* g1 = (const float*)d_in[16], *b1 = (const float*)d_in[17];
  const float* iw = (const float*)d_in[18], *ib = (const float*)d_in[19];
  const float* ow = (const float*)d_in[20], *ob = (const float*)d_in[21];
  const float* g2 = (const float*)d_in[22], *b2 = (const float*)d_in[23];

  float* out_outs = (float*)d_out;
  float* out_adj  = out_outs + SZ_BNH;

  // ---- workspace carve (~190 MB). out_outs doubles as fp32 scratch sc2. ----
  char* p = (char*)d_ws;
  float* cur  = (float*)carve(p, SZ_BNH*4);
  float* sc1  = (float*)carve(p, SZ_BNH*4);
  float* fo   = (float*)carve(p, SZ_BNH*4);
  float* S    = (float*)carve(p, SZ_BNN*4);           // fp32 scores / logits
  bf16*  Rb   = (bf16*)carve(p, SZ_BNN*2*2);          // attnP / p_row pair
  bf16*  Rc   = (bf16*)carve(p, SZ_BNN*2*2);          // p_col^T pair
  bf16*  T1   = (bf16*)carve(p, SZ_PAD*2);
  bf16*  T2   = (bf16*)carve(p, SZ_PAD*2);
  bf16*  T3   = (bf16*)carve(p, SZ_PAD*2);
  bf16*  T4   = (bf16*)carve(p, SZ_PAD*2);
  bf16*  T5   = (bf16*)carve(p, SZ_PAD*2);
  bf16*  T6   = (bf16*)carve(p, SZ_PAD*2);
  bf16*  TA1  = (bf16*)carve(p, SZ_PAD*2);            // cur / new_outs pair
  bf16*  TA2  = (bf16*)carve(p, SZ_PAD*2);
  bf16*  TF1  = (bf16*)carve(p, SZ_PAD*2);            // fo pair (row-tiled)
  bf16*  TF2  = (bf16*)carve(p, SZ_PAD*2);
  bf16*  TT1  = (bf16*)carve(p, SZ_PAD*2);            // fo^T pair (from sk5)
  bf16*  TT2  = (bf16*)carve(p, SZ_PAD*2);
  bf16*  ADJB = (bf16*)carve(p, SZ_BNN*2);            // adj bf16 tiled (const)
  bf16*  Wh_all = (bf16*)carve(p, (size_t)21*HP*HP*2);   // +1 slack slot
  bf16*  Wl_all = (bf16*)carve(p, (size_t)21*HP*HP*2);
  float* cpm     = (float*)carve(p, (size_t)8*BN*4);  // col-stat partials
  float* cps     = (float*)carve(p, (size_t)8*BN*4);
  float* denom   = (float*)carve(p, BN*4);
  float* maskf   = (float*)carve(p, BN*4);
  float* maskadd = (float*)carve(p, BN*4);
  float* cmaxv   = (float*)carve(p, BN*4);
  float* csumv   = (float*)carve(p, BN*4);

  float* sc2 = out_outs;          // fp32 scratch; final sk6 overwrites in iter 2
  bf16* attnP = Rb;
  bf16* Ph    = Rb;
  bf16* Pl    = Rb + SZ_BNN;
  bf16* PcH   = Rc;
  bf16* PcL   = Rc + SZ_BNN;

  const size_t sNT = (size_t)Nd*HP;     // batch stride (tiled), 1024*224
  const size_t sT  = (size_t)HP*Nd;     // batch stride (tiled), 224*1024
  const size_t sNN = (size_t)Nd*Nd;     // batch stride, 1024*1024

  #define W_GCN 0
  #define W_MUT 1
  #define W_Q(i) (2 + (i))
  #define W_K(i) (5 + (i))
  #define W_V(i) (8 + (i))
  #define W_AO(i) (11 + (i))
  #define W_IW(i) (14 + (i))
  #define W_OW(i) (17 + (i))
  #define WH(s) (Wh_all + (size_t)(s)*HP*HP)
  #define WL(s) (Wl_all + (size_t)(s)*HP*HP)

  dim3 blk256(256);
  dim3 gPad((unsigned)((SZ_PAD+255)/256));
  dim3 gPadT(32, 7, Bd), bT(32, 8);
  dim3 gWall((HP*HP+255)/256, 20);
  dim3 gCvt(32, 128, Bd);
  dim3 gBNH((unsigned)((SZ_BNH+255)/256));
  dim3 gSm(4, 128, 1);       // small GEMM: 16x64/wave (RI=1), 8192 rows, K=HP
  dim3 gQKV(4, 128, 3);      // merged Q/K/V
  dim3 gNT(16, 8, Bd);       // scores/logits: 32x64/wave (RI=2), K=HP
  dim3 gSK(32, 4, Bd);       // split-K=4 mixes: 32-row blocks
  const float inv_sqrt_h = 0.07071067811865475f;  // 1/sqrt(200)
  const size_t Z = 0;
  float* FN = nullptr;
  bf16*  BN_ = nullptr;

  k_prep_masks<<<(BN+255)/256, blk256, 0, stream>>>(textmask, maskf, maskadd);
  k_prep_adj<<<BN, blk256, 0, stream>>>(adj1, adj2, out_adj, denom);
  k_copy2<<<gBNH, blk256, 0, stream>>>(text, cur, fo);
  c_w_split_all<<<gWall, blk256, 0, stream>>>(gcn_w, mut_w, qw, kw, vw, aow, iw, ow,
                                              Wh_all, Wl_all);
  c_pad_split<<<gPad, blk256, 0, stream>>>(text, TA1, TA2);   // BERT-in pair (iter 0)
  c_pad_split<<<gPad, blk256, 0, stream>>>(text, TF1, TF2);   // fo pair (iter 0)
  c_cvt1024_t<<<gCvt, blk256, 0, stream>>>(out_adj, ADJB);    // adj bf16 (const)

  for (int i = 0; i < 3; i++){
    const float *qbi = qb + i*Hd;
    const float *kbi = kb + i*Hd;
    const float *vbi = vb + i*Hd;
    const float *aobi= aob+ i*Hd;
    const float *g1i = g1 + i*Hd,    *b1i = b1 + i*Hd;
    const float *ibi = ib + i*Hd;
    const float *obi = ob + i*Hd;
    const float *g2i = g2 + i*Hd,    *b2i = b2 + i*Hd;

    // ================= BERT layer =================
    k_qkv<<<gQKV, blk256, 0, stream>>>(TA1,TA2, WH(W_Q(i)),WL(W_Q(i)),
              T3,T4, T5,T6, T1,T2, qbi,kbi,vbi);                            // Q,K pairs + V^T pair
    k_mfma3<3,3,2,HP><<<gNT, blk256, 0, stream>>>(T3,T4,T5,T6, S,BN_,BN_,
              nullptr, maskadd,nullptr, sNT,sNT, inv_sqrt_h, FN,FN);        // scores
    k_rowsoftmax<0><<<BN, blk256, 0, stream>>>(S, attnP, BN_, FN,FN, BN_,BN_);
    k_mfma3sk<8,2,Nd><<<gSK, blk256, 0, stream>>>(attnP,BN_,T1,T2,
              FN,T3,T4, FN,FN,FN, sNN,sT, BN_,BN_);                         // ctx pair
    k_mfma3<0,3,1,HP><<<gSm, blk256, 0, stream>>>(T3,T4,WH(W_AO(i)),WL(W_AO(i)),
              sc1,BN_,BN_, aobi, FN,FN, Z,Z, 0.f, FN,FN);                   // ao_out fp32
    k_add_ln<<<BN, blk256, 0, stream>>>(sc1, cur, g1i, b1i, sc2, T1, T2);   // ln1 + pair
    k_mfma3<10,3,1,HP><<<gSm, blk256, 0, stream>>>(T1,T2,WH(W_IW(i)),WL(W_IW(i)),
              FN,T3,T4, ibi, FN,FN, Z,Z, 0.f, FN,FN);                       // gelu pair
    k_mfma3<0,3,1,HP><<<gSm, blk256, 0, stream>>>(T3,T4,WH(W_OW(i)),WL(W_OW(i)),
              cur,BN_,BN_, obi, FN,FN, Z,Z, 0.f, FN,FN);                    // ow_out fp32
    k_add_ln<<<BN, blk256, 0, stream>>>(cur, sc2, g2i, b2i, cur, TA1, TA2); // ln2 + pair

    // ================= GCN on fo =================
    k_mfma3<9,3,1,HP><<<gSm, blk256, 0, stream>>>(TF1,TF2,WH(W_GCN),WL(W_GCN),
              FN,T1,T2, nullptr, FN,FN, Z,Z, 0.f, FN,FN);                   // teout^T pair
    k_mfma3sk<5,2,Nd><<<gSK, blk256, 0, stream>>>(ADJB,BN_,T1,T2,
              fo,TF1,TF2, denom,FN,FN, sNN,sT, TT1,TT2);                    // fo update + pair + fo^T

    // ================= self-alignment =================
    k_mfma3<2,3,1,HP><<<gSm, blk256, 0, stream>>>(TA1,TA2,WH(W_MUT),WL(W_MUT),
              FN,T5,T6, nullptr, FN,FN, Z,Z, 0.f, FN,FN);                   // mm pair
    k_mfma3<4,3,2,HP><<<gNT, blk256, 0, stream>>>(T5,T6,TF1,TF2, S,BN_,BN_,
              nullptr, nullptr,maskf, sNT,sNT, 0.f, cpm,cps);               // logits + col partials
    k_colcomb<<<BN/256, blk256, 0, stream>>>(cpm, cps, cmaxv, csumv);
    k_rowsoftmax<2><<<BN, blk256, 0, stream>>>(S, Ph, Pl, cmaxv, csumv, PcH, PcL);
    c_padT_split<<<gPadT, bT, 0, stream>>>(cur, T3, T4);                    // outs^T (POST-BERT cur)
    k_mfma3sk<6,3,Nd><<<gSK, blk256, 0, stream>>>(Ph,Pl,TT1,TT2,
              (i==2)?out_outs:sc1, TA1,TA2, FN,maskf,cur, sNN,sT, BN_,BN_); // new_outs + pair
    k_mfma3sk<7,3,Nd><<<gSK, blk256, 0, stream>>>(PcH,PcL,T3,T4,
              fo,TF1,TF2, FN,maskf,FN, sNN,sT, BN_,BN_);                    // fo update + pair

    float* t = cur; cur = sc1; sc1 = t;          // outs = new_outs (fp32 chain)
  }
}

// Round 10
// 1104.175 us; speedup vs baseline: 1.1938x; 1.0355x over previous
//
#include <hip/hip_runtime.h>
#include <hip/hip_bf16.h>
#include <math.h>

// Problem constants
#define Bd 8
#define Nd 1024
#define Hd 200
#define HP 224                      // Hd padded to multiple of 32
#define BN (Bd*Nd)                  // 8192
#define SZ_BNH ((size_t)BN*Hd)      // 1,638,400
#define SZ_BNN ((size_t)BN*Nd)      // 8,388,608
#define SZ_PAD ((size_t)BN*HP)      // 1,835,008

typedef __hip_bfloat16 bf16;
typedef __attribute__((ext_vector_type(8))) short bf16x8;   // 8 bf16 = 4 VGPRs (A/B frag)
typedef __attribute__((ext_vector_type(4))) float f32x4;    // C/D frag
typedef __attribute__((ext_vector_type(4))) short s16x4;    // 4 bf16 = 8B store

__device__ __forceinline__ float bf2f(bf16 v){ return __bfloat162float(v); }
__device__ __forceinline__ bf16 f2bf(float v){ return __float2bfloat16(v); }
__device__ __forceinline__ short bfb(float v){ bf16 h = f2bf(v); return *(short*)&h; }
__device__ __forceinline__ short lowb(float v){
  bf16 h = f2bf(v); bf16 l = f2bf(v - bf2f(h)); return *(short*)&l;
}

#define MFMA16(a,b,c) __builtin_amdgcn_mfma_f32_16x16x32_bf16((a),(b),(c),0,0,0)

// Fragment-native tiled layout. Element (row, k) of a [R][KP] matrix lives at:
//   (row>>4)*16*KP + (k>>5)*512 + ((k>>3)&3)*128 + (row&15)*8 + (k&7)
__device__ __forceinline__ size_t tidx1024(int row, int k){
  return (size_t)(row>>4)*16384 + (size_t)((k>>5))*512
       + (size_t)(((k>>3)&3))*128 + (size_t)(row&15)*8 + (k&7);
}
__device__ __forceinline__ size_t tidxHP(int row, int k){
  return (size_t)(row>>4)*3584 + (size_t)((k>>5))*512
       + (size_t)(((k>>3)&3))*128 + (size_t)(row&15)*8 + (k&7);
}

// ============================ prep (fp32) ============================
__global__ void k_prep_masks(const float* __restrict__ tm, float* __restrict__ maskf,
                             float* __restrict__ maskadd){
  int i = blockIdx.x*256 + threadIdx.x;
  if (i < BN){ float m = tm[i]; maskf[i] = m; maskadd[i] = (1.f - m) * -10000.f; }
}

__global__ void k_prep_adj(const float* __restrict__ a1, const float* __restrict__ a2,
                           float* __restrict__ adj_out, float* __restrict__ denom){
  int r = blockIdx.x;
  const size_t base = (size_t)r * Nd;
  int t = threadIdx.x;
  float s = 0.f;
  for (int m = t; m < Nd; m += 256){
    float a = a1[base+m] + a2[base+m];
    a = a >= 1.f ? 1.f : a;
    adj_out[base+m] = a;
    s += a;
  }
  __shared__ float red[256];
  red[t] = s; __syncthreads();
  for (int st = 128; st > 0; st >>= 1){ if (t < st) red[t] += red[t+st]; __syncthreads(); }
  if (t == 0) denom[r] = red[0] + 1e-07f;
}

__global__ void k_copy2(const float* __restrict__ x, float* __restrict__ o1,
                        float* __restrict__ o2){
  size_t i = (size_t)blockIdx.x*256 + threadIdx.x;
  if (i < SZ_BNH){ float v = x[i]; o1[i] = v; o2[i] = v; }
}

// ============================ split conversions ============================
__global__ void c_pad_split(const float* __restrict__ X, bf16* __restrict__ Oh,
                            bf16* __restrict__ Ol){
  size_t o = (size_t)blockIdx.x*256 + threadIdx.x;
  if (o >= SZ_PAD) return;
  int oi = (int)o;
  int panel = oi / 3584;             // 16*HP
  int rem   = oi % 3584;
  int kt  = rem >> 9;
  int kg  = (rem >> 7) & 3;
  int r16 = (rem >> 3) & 15;
  int ke  = rem & 7;
  int row = panel*16 + r16;
  int k   = kt*32 + kg*8 + ke;
  float v = (k < Hd) ? X[(size_t)row*Hd + k] : 0.f;
  bf16 h = f2bf(v);
  Oh[o] = h; Ol[o] = f2bf(v - bf2f(h));
}

// Transpose-pad-split writing the TILED-1024 layout (row = d, k = m).
__global__ void c_padT_split(const float* __restrict__ X, bf16* __restrict__ Oh,
                             bf16* __restrict__ Ol){
  __shared__ float t[32][33];
  int b = blockIdx.z, m0 = blockIdx.x*32, d0 = blockIdx.y*32;
  int tx = threadIdx.x, ty = threadIdx.y;          // block (32,8)
  for (int i = ty; i < 32; i += 8){
    int d = d0 + tx;
    t[i][tx] = (d < Hd) ? X[((size_t)b*Nd + m0+i)*Hd + d] : 0.f;
  }
  __syncthreads();
  for (int i = ty; i < 32; i += 8){
    int row = d0 + i, kk = m0 + tx;
    size_t idx = (size_t)b*229376 + tidx1024(row, kk);
    float v = t[tx][i];
    bf16 h = f2bf(v);
    Oh[idx] = h; Ol[idx] = f2bf(v - bf2f(h));
  }
}

// Batched weight split -> TILED layout.
// mi: 0=gcn 1=mut 2..4=qw 5..7=kw 8..10=vw 11..13=aow 14..16=iw 17..19=ow
__global__ void c_w_split_all(const float* __restrict__ g, const float* __restrict__ m,
                              const float* __restrict__ q, const float* __restrict__ k,
                              const float* __restrict__ v, const float* __restrict__ ao,
                              const float* __restrict__ iw, const float* __restrict__ ow,
                              bf16* __restrict__ Oh, bf16* __restrict__ Ol){
  int mi = blockIdx.y;
  const float* W;
  if (mi == 0) W = g;
  else if (mi == 1) W = m;
  else {
    int gi = (mi-2)/3, si = (mi-2)%3;
    const float* bs[6] = {q, k, v, ao, iw, ow};
    W = bs[gi] + (size_t)si*Hd*Hd;
  }
  int o = blockIdx.x*256 + threadIdx.x;
  if (o >= HP*HP) return;
  int panel = o / 3584;
  int rem   = o % 3584;
  int kt  = rem >> 9;
  int kg  = (rem >> 7) & 3;
  int r16 = (rem >> 3) & 15;
  int ke  = rem & 7;
  int n   = panel*16 + r16;          // output col (B-matrix row)
  int kk  = kt*32 + kg*8 + ke;
  float val = (n < Hd && kk < Hd) ? W[kk*Hd + n] : 0.f;
  bf16 h = f2bf(val);
  Oh[(size_t)mi*HP*HP + o] = h; Ol[(size_t)mi*HP*HP + o] = f2bf(val - bf2f(h));
}

// adj -> bf16 tiled-1024 (once; adj constant across iterations).
__global__ void c_cvt1024_t(const float* __restrict__ X, bf16* __restrict__ O){
  int b = blockIdx.z, kg = blockIdx.x, rg = blockIdx.y;
  int r = threadIdx.x >> 5, kl = threadIdx.x & 31;
  int row = rg*8 + r, k = kg*32 + kl;
  float v = X[(size_t)b*1048576 + (size_t)row*1024 + k];
  O[(size_t)b*1048576 + tidx1024(row, k)] = f2bf(v);
}

// ============================ fused row softmax (attention, 1 row/block) =========
// Register-resident float4; 1 __expf per element; vectorized p_row store.
__global__ __launch_bounds__(256)
void k_rowsoftmax0(const float* __restrict__ S, bf16* __restrict__ Ph){
  __shared__ float red[256];
  size_t bid = blockIdx.x;
  size_t r = ((bid & 7) << 10) + (bid >> 3);     // batch = bid&7, slot = bid>>3
  int t = threadIdx.x;
  const f32x4 v4 = *(const f32x4*)(S + r*Nd + t*4);
  float mx = fmaxf(fmaxf(v4[0], v4[1]), fmaxf(v4[2], v4[3]));
  red[t] = mx; __syncthreads();
  for (int s = 128; s > 0; s >>= 1){ if (t < s) red[t] = fmaxf(red[t], red[t+s]); __syncthreads(); }
  mx = red[0]; __syncthreads();
  float e0 = __expf(v4[0] - mx), e1 = __expf(v4[1] - mx);
  float e2 = __expf(v4[2] - mx), e3 = __expf(v4[3] - mx);
  red[t] = (e0 + e1) + (e2 + e3); __syncthreads();
  for (int s = 128; s > 0; s >>= 1){ if (t < s) red[t] += red[t+s]; __syncthreads(); }
  float inv = 1.f / red[0];
  size_t obase = ((r >> 10) << 20) + (size_t)(((int)(r & 1023)) >> 4)*16384
               + (size_t)((int)r & 15)*8;
  int i = t*4;
  size_t idx = obase + (size_t)(i>>5)*512 + (size_t)((i>>3)&3)*128 + (i&7);
  s16x4 hv = { bfb(e0*inv), bfb(e1*inv), bfb(e2*inv), bfb(e3*inv) };
  *(s16x4*)(Ph + idx) = hv;
}

// ==================== fused dual softmax, 8 rows/block (self-alignment) =========
// Block handles rows n0..n0+7 of batch bq. Phase 1: 32-lane groups (r_loc=t>>5)
// do register-resident row softmax (1 __expf/elem, shfl_xor reduce) and write
// the p_row pair; raw S values staged in LDS (stride 1028 -> conflict-free
// 8-way column reads). Phase 2: thread t owns m=4t..4t+3; for each m the 8
// n-values pack into ONE 16B bf16x8 store per buffer -> every output 128B line
// is fully written by this block in 16B granules (vs 2B scatter before).
__global__ __launch_bounds__(256)
void k_rowsm8(const float* __restrict__ S, bf16* __restrict__ Ph,
              bf16* __restrict__ Pl, const float* __restrict__ cmax,
              const float* __restrict__ csum, bf16* __restrict__ PcH,
              bf16* __restrict__ PcL){
  __shared__ float rows[8][1028];
  int bq = blockIdx.x & 7;
  int rg = blockIdx.x >> 3;            // row-group 0..127
  int n0 = rg*8;
  int t = threadIdx.x;
  int r_loc = t >> 5, j = t & 31;
  size_t r = ((size_t)bq << 10) + n0 + r_loc;
  const float* src = S + r*Nd;
  f32x4 v[8];
  float mx = -3.4e38f;
  #pragma unroll
  for (int kk = 0; kk < 8; kk++){
    v[kk] = *(const f32x4*)(src + kk*128 + j*4);
    *(f32x4*)(&rows[r_loc][kk*128 + j*4]) = v[kk];
    mx = fmaxf(mx, fmaxf(fmaxf(v[kk][0], v[kk][1]), fmaxf(v[kk][2], v[kk][3])));
  }
  #pragma unroll
  for (int off = 16; off >= 1; off >>= 1) mx = fmaxf(mx, __shfl_xor(mx, off));
  float e[8][4];
  float sum = 0.f;
  #pragma unroll
  for (int kk = 0; kk < 8; kk++){
    #pragma unroll
    for (int q = 0; q < 4; q++){ e[kk][q] = __expf(v[kk][q] - mx); }
    sum += (e[kk][0] + e[kk][1]) + (e[kk][2] + e[kk][3]);
  }
  #pragma unroll
  for (int off = 16; off >= 1; off >>= 1) sum += __shfl_xor(sum, off);
  float inv = 1.f / sum;
  size_t obase = ((size_t)bq << 20) + (size_t)((n0 + r_loc) >> 4)*16384
               + (size_t)((n0 + r_loc) & 15)*8;
  #pragma unroll
  for (int kk = 0; kk < 8; kk++){
    int i = kk*128 + j*4;
    size_t idx = obase + (size_t)(i>>5)*512 + (size_t)((i>>3)&3)*128 + (i&7);
    float p0 = e[kk][0]*inv, p1 = e[kk][1]*inv, p2 = e[kk][2]*inv, p3 = e[kk][3]*inv;
    s16x4 hv = { bfb(p0), bfb(p1), bfb(p2), bfb(p3) };
    *(s16x4*)(Ph + idx) = hv;
    s16x4 lv = { lowb(p0), lowb(p1), lowb(p2), lowb(p3) };
    *(s16x4*)(Pl + idx) = lv;
  }
  __syncthreads();
  // Phase 2: p_col^T, 16B-packed writes
  const f32x4 c4 = *(const f32x4*)(cmax + bq*Nd + t*4);
  const f32x4 s4 = *(const f32x4*)(csum + bq*Nd + t*4);
  size_t nb = (size_t)bq*1048576 + (size_t)(rg>>2)*512 + (size_t)(rg&3)*128;
  #pragma unroll
  for (int mi = 0; mi < 4; mi++){
    int m = t*4 + mi;
    float cm = c4[mi], ci = 1.f / s4[mi];
    bf16x8 hv, lv;
    #pragma unroll
    for (int rr = 0; rr < 8; rr++){
      float p = __expf(rows[rr][m] - cm) * ci;
      bf16 h = f2bf(p);
      hv[rr] = *(short*)&h;
      bf16 l = f2bf(p - bf2f(h));
      lv[rr] = *(short*)&l;
    }
    size_t idx = nb + (size_t)(m>>4)*16384 + (size_t)(m&15)*8;
    *(bf16x8*)(PcH + idx) = hv;
    *(bf16x8*)(PcL + idx) = lv;
  }
}

// Combine 8 per-rowblock column partials into final column stats.
__global__ void k_colcomb(const float* __restrict__ cpm, const float* __restrict__ cps,
                          float* __restrict__ cmax, float* __restrict__ csum){
  int i = blockIdx.x*256 + threadIdx.x;    // global col b*1024+m
  float M = cpm[i], S = cps[i];
  #pragma unroll
  for (int y = 1; y < 8; y++){
    float m2 = cpm[(size_t)y*BN + i], s2 = cps[(size_t)y*BN + i];
    float Mn = fmaxf(M, m2);
    S = S*__expf(M - Mn) + s2*__expf(m2 - Mn);
    M = Mn;
  }
  cmax[i] = M; csum[i] = S;
}

// ============================ residual + layernorm (+ optional pair out) =========
__global__ void k_add_ln(const float* __restrict__ X, const float* __restrict__ R,
                         const float* __restrict__ g, const float* __restrict__ bb,
                         float* __restrict__ Y, bf16* __restrict__ Ph,
                         bf16* __restrict__ Pl){
  int r = blockIdx.x, t = threadIdx.x;
  __shared__ float red[256];
  bool act = t < Hd;
  float v = 0.f;
  if (act) v = X[(size_t)r*Hd + t] + R[(size_t)r*Hd + t];
  red[t] = act ? v : 0.f; __syncthreads();
  for (int s = 128; s > 0; s >>= 1){ if (t < s) red[t] += red[t+s]; __syncthreads(); }
  float mu = red[0] * (1.f/Hd); __syncthreads();
  float d = act ? (v - mu) : 0.f;
  red[t] = d*d; __syncthreads();
  for (int s = 128; s > 0; s >>= 1){ if (t < s) red[t] += red[t+s]; __syncthreads(); }
  float var = red[0] * (1.f/Hd);
  float o = 0.f;
  if (act){
    float rs = 1.f / sqrtf(var + 1e-20f);
    o = (v - mu) * rs * g[t] + bb[t];
    Y[(size_t)r*Hd + t] = o;
  }
  if (Ph && t < HP){
    bf16 h = f2bf(o);
    size_t idx = tidxHP(r, t);
    Ph[idx] = h; Pl[idx] = f2bf(o - bf2f(h));
  }
}

// ============================ merged Q/K/V GEMM ============================
// blockIdx.z = slice: 0=Q (pair->QH/QL), 1=K (pair->KH/KL), 2=V (transposed pair
// ->VH/VL via LDS). Weight slot base Wh0/Wl0 = Q slot; slice stride 3 slots.
__global__ __launch_bounds__(256)
void k_qkv(const bf16* __restrict__ Ah, const bf16* __restrict__ Al,
           const bf16* __restrict__ Wh0, const bf16* __restrict__ Wl0,
           bf16* __restrict__ QH, bf16* __restrict__ QL,
           bf16* __restrict__ KH, bf16* __restrict__ KL,
           bf16* __restrict__ VH, bf16* __restrict__ VL,
           const float* __restrict__ qb, const float* __restrict__ kb,
           const float* __restrict__ vb)
{
  constexpr int KP = HP;
  constexpr int STEPS = KP/32;
  int slice = blockIdx.z;
  int wave = threadIdx.x >> 6, lane = threadIdx.x & 63;
  int r0 = (blockIdx.y*4 + wave)*16;
  int c0 = blockIdx.x*64;
  int lm = lane & 15, lq = lane >> 4;
  const size_t PST = (size_t)16*KP;
  const size_t aT = (size_t)(r0>>4)*PST + (size_t)lane*8;
  const size_t bT = (size_t)slice*3*HP*HP + (size_t)(c0>>4)*PST + (size_t)lane*8;

  f32x4 acc[4] = {};
  bf16x8 pah[2], pal[2], pbh[2][4], pbl[2][4];
  pah[0] = *(const bf16x8*)(Ah + aT);
  pal[0] = *(const bf16x8*)(Al + aT);
  #pragma unroll
  for (int j = 0; j < 4; j++){
    pbh[0][j] = *(const bf16x8*)(Wh0 + bT + (size_t)j*PST);
    pbl[0][j] = *(const bf16x8*)(Wl0 + bT + (size_t)j*PST);
  }
  #pragma unroll
  for (int ki = 0; ki < STEPS; ki++){
    const int cb = ki & 1, nb = cb ^ 1;
    if (ki + 1 < STEPS){
      const size_t kn = (size_t)(ki+1)*512;
      pah[nb] = *(const bf16x8*)(Ah + aT + kn);
      pal[nb] = *(const bf16x8*)(Al + aT + kn);
      #pragma unroll
      for (int j = 0; j < 4; j++){
        pbh[nb][j] = *(const bf16x8*)(Wh0 + bT + (size_t)j*PST + kn);
        pbl[nb][j] = *(const bf16x8*)(Wl0 + bT + (size_t)j*PST + kn);
      }
    }
    #pragma unroll
    for (int j = 0; j < 4; j++) acc[j] = MFMA16(pah[cb], pbh[cb][j], acc[j]);
    #pragma unroll
    for (int j = 0; j < 4; j++) acc[j] = MFMA16(pah[cb], pbl[cb][j], acc[j]);
    #pragma unroll
    for (int j = 0; j < 4; j++) acc[j] = MFMA16(pal[cb], pbh[cb][j], acc[j]);
  }

  const float* bias = (slice == 0) ? qb : (slice == 1) ? kb : vb;
  if (slice < 2){
    bf16* Oh = (slice == 0) ? QH : KH;
    bf16* Ol = (slice == 0) ? QL : KL;
    #pragma unroll
    for (int j = 0; j < 4; j++){
      int col = c0 + j*16 + lm;
      if (col >= HP) continue;
      #pragma unroll
      for (int r = 0; r < 4; r++){
        int row = r0 + lq*4 + r;
        float o = (col < Hd) ? acc[j][r] + bias[col] : 0.f;
        bf16 h = f2bf(o);
        size_t idx = tidxHP(row, col);
        Oh[idx] = h; Ol[idx] = f2bf(o - bf2f(h));
      }
    }
  } else {
    __shared__ float tl[64][65];
    #pragma unroll
    for (int j = 0; j < 4; j++)
      #pragma unroll
      for (int r = 0; r < 4; r++)
        tl[wave*16 + lq*4 + r][j*16 + lm] = acc[j][r];
    __syncthreads();
    int b2 = (int)((blockIdx.y*64) >> 10);
    int m0 = (int)((blockIdx.y*64) & 1023);
    #pragma unroll
    for (int e = threadIdx.x; e < 4096; e += 256){
      int pan = e >> 10, rem = e & 1023;
      int r16 = (rem >> 3) & 15;
      int d = c0 + pan*16 + r16;
      if (d >= HP) continue;
      int kg = (rem >> 7) & 3;
      int k_loc = (rem >> 9)*32 + kg*8 + (rem & 7);
      float val = 0.f;
      if (d < Hd) val = tl[k_loc][pan*16 + r16] + bias[d];
      bf16 h = f2bf(val);
      size_t idx = (size_t)b2*229376 + (size_t)(d>>4)*16384
                 + (size_t)((m0 + k_loc)>>5)*512 + (size_t)kg*128
                 + (size_t)r16*8 + (rem & 7);
      VH[idx] = h; VL[idx] = f2bf(val - bf2f(h));
    }
  }
}

// ============================ split-precision MFMA GEMM (no split-K) ============
// EPI: 0 fp32 Y=acc+bias   2 split-bf16 row-tiled pair out (+bias)
//      3 S=acc*scale+maskadd[col]   4 S=acc+pairmask (+ column-stats partials)
//      9 TRANSPOSED tiled pair out (+bias) via LDS   10 gelu -> row-tiled pair
template<int EPI, int TERMS, int RI, int KP>
__global__ __launch_bounds__(256)
void k_mfma3(const bf16* __restrict__ Ah, const bf16* __restrict__ Al,
             const bf16* __restrict__ Bh, const bf16* __restrict__ Bl,
             float* __restrict__ Y, bf16* __restrict__ Ybh, bf16* __restrict__ Ybl,
             const float* __restrict__ bias, const float* __restrict__ e0,
             const float* __restrict__ e1,
             size_t sAb, size_t sBb, float scale,
             float* __restrict__ cpm, float* __restrict__ cps)
{
  int b = blockIdx.z;
  int wave = threadIdx.x >> 6, lane = threadIdx.x & 63;
  int r0 = (blockIdx.y*4 + wave)*(RI*16);
  int c0 = blockIdx.x*64;
  int lm = lane & 15, lq = lane >> 4;
  const size_t PST = (size_t)16*KP;     // panel stride (elements)
  const size_t aT = (size_t)b*sAb + (size_t)(r0>>4)*PST + (size_t)lane*8;
  const size_t bT = (size_t)b*sBb + (size_t)(c0>>4)*PST + (size_t)lane*8;
  constexpr int STEPS = KP/32;

  f32x4 acc[RI][4] = {};
  bf16x8 pah[2][RI], pal[2][RI], pbh[2][4], pbl[2][4];
  {
    #pragma unroll
    for (int i = 0; i < RI; i++) pah[0][i] = *(const bf16x8*)(Ah + aT + (size_t)i*PST);
    #pragma unroll
    for (int j = 0; j < 4; j++){
      pbh[0][j] = *(const bf16x8*)(Bh + bT + (size_t)j*PST);
      pbl[0][j] = *(const bf16x8*)(Bl + bT + (size_t)j*PST);
    }
    if (TERMS >= 3){
      #pragma unroll
      for (int i = 0; i < RI; i++) pal[0][i] = *(const bf16x8*)(Al + aT + (size_t)i*PST);
    }
  }

  #pragma unroll
  for (int ki = 0; ki < STEPS; ki++){
    const int cb = ki & 1, nb = cb ^ 1;
    if (ki + 1 < STEPS){
      const size_t kn = (size_t)(ki+1)*512;
      #pragma unroll
      for (int i = 0; i < RI; i++) pah[nb][i] = *(const bf16x8*)(Ah + aT + (size_t)i*PST + kn);
      #pragma unroll
      for (int j = 0; j < 4; j++){
        pbh[nb][j] = *(const bf16x8*)(Bh + bT + (size_t)j*PST + kn);
        pbl[nb][j] = *(const bf16x8*)(Bl + bT + (size_t)j*PST + kn);
      }
      if (TERMS >= 3){
        #pragma unroll
        for (int i = 0; i < RI; i++) pal[nb][i] = *(const bf16x8*)(Al + aT + (size_t)i*PST + kn);
      }
    }
    #pragma unroll
    for (int i = 0; i < RI; i++)
      #pragma unroll
      for (int j = 0; j < 4; j++) acc[i][j] = MFMA16(pah[cb][i], pbh[cb][j], acc[i][j]);
    #pragma unroll
    for (int i = 0; i < RI; i++)
      #pragma unroll
      for (int j = 0; j < 4; j++) acc[i][j] = MFMA16(pah[cb][i], pbl[cb][j], acc[i][j]);
    if (TERMS >= 3){
      #pragma unroll
      for (int i = 0; i < RI; i++)
        #pragma unroll
        for (int j = 0; j < 4; j++) acc[i][j] = MFMA16(pal[cb][i], pbh[cb][j], acc[i][j]);
    }
  }

  if constexpr (EPI == 9){
    __shared__ float tl[64][65];
    #pragma unroll
    for (int j = 0; j < 4; j++)
      #pragma unroll
      for (int r = 0; r < 4; r++)
        tl[wave*16 + lq*4 + r][j*16 + lm] = acc[0][j][r];
    __syncthreads();
    int b2 = (int)((blockIdx.y*64) >> 10);
    int m0 = (int)((blockIdx.y*64) & 1023);
    #pragma unroll
    for (int e = threadIdx.x; e < 4096; e += 256){
      int pan = e >> 10, rem = e & 1023;
      int r16 = (rem >> 3) & 15;
      int d = c0 + pan*16 + r16;
      if (d >= HP) continue;
      int kg = (rem >> 7) & 3;
      int k_loc = (rem >> 9)*32 + kg*8 + (rem & 7);
      float val = 0.f;
      if (d < Hd) val = tl[k_loc][pan*16 + r16] + (bias ? bias[d] : 0.f);
      bf16 h = f2bf(val);
      size_t idx = (size_t)b2*229376 + (size_t)(d>>4)*16384
                 + (size_t)((m0 + k_loc)>>5)*512 + (size_t)kg*128
                 + (size_t)r16*8 + (rem & 7);
      Ybh[idx] = h; Ybl[idx] = f2bf(val - bf2f(h));
    }
  } else if constexpr (EPI == 4){
    // logits + per-block column-softmax partials (max, sum-exp over 128 rows)
    float er[RI][4];
    #pragma unroll
    for (int i = 0; i < RI; i++)
      #pragma unroll
      for (int r = 0; r < 4; r++)
        er[i][r] = e1[b*Nd + r0 + i*16 + lq*4 + r];
    float cm[4], cs[4];
    #pragma unroll
    for (int j = 0; j < 4; j++){
      int col = c0 + j*16 + lm;
      float e1c = e1[b*Nd + col];
      float wv[RI][4];
      float mloc = -3.4e38f;
      #pragma unroll
      for (int i = 0; i < RI; i++){
        #pragma unroll
        for (int r = 0; r < 4; r++){
          int row = r0 + i*16 + lq*4 + r;
          float w = acc[i][j][r] + (1.f - er[i][r]*e1c)*(-10000.f);
          Y[((size_t)b*Nd + row)*Nd + col] = w;
          wv[i][r] = w;
          mloc = fmaxf(mloc, w);
        }
      }
      float sloc = 0.f;
      #pragma unroll
      for (int i = 0; i < RI; i++)
        #pragma unroll
        for (int r = 0; r < 4; r++) sloc += __expf(wv[i][r] - mloc);
      cm[j] = mloc; cs[j] = sloc;
    }
    #pragma unroll
    for (int j = 0; j < 4; j++){
      float m = cm[j], s = cs[j];
      #pragma unroll
      for (int off = 16; off <= 32; off <<= 1){
        float m2 = __shfl_xor(m, off), s2 = __shfl_xor(s, off);
        float M = fmaxf(m, m2);
        s = s*__expf(m - M) + s2*__expf(m2 - M);
        m = M;
      }
      cm[j] = m; cs[j] = s;
    }
    __shared__ float pmx[4][4][16], psm[4][4][16];
    if (lq == 0){
      #pragma unroll
      for (int j = 0; j < 4; j++){ pmx[wave][j][lm] = cm[j]; psm[wave][j][lm] = cs[j]; }
    }
    __syncthreads();
    if (threadIdx.x < 64){
      int t = threadIdx.x;             // col-in-block = t (j=t>>4, lm=t&15)
      int jj = t >> 4, cc = t & 15;
      float M = pmx[0][jj][cc], S = psm[0][jj][cc];
      #pragma unroll
      for (int w = 1; w < 4; w++){
        float m2 = pmx[w][jj][cc], s2 = psm[w][jj][cc];
        float Mn = fmaxf(M, m2);
        S = S*__expf(M - Mn) + s2*__expf(m2 - Mn);
        M = Mn;
      }
      size_t pi = (size_t)blockIdx.y*BN + (size_t)b*Nd + c0 + t;
      cpm[pi] = M; cps[pi] = S;
    }
  } else {
    #pragma unroll
    for (int i = 0; i < RI; i++){
      #pragma unroll
      for (int j = 0; j < 4; j++){
        int col = c0 + j*16 + lm;
        int rbase = r0 + i*16 + lq*4;
        #pragma unroll
        for (int r = 0; r < 4; r++){
          int row = rbase + r;
          size_t rowg = (size_t)b*Nd + row;
          float v = acc[i][j][r];
          if (EPI == 0){
            if (col < Hd){
              v += bias ? bias[col] : 0.f;
              Y[rowg*Hd + col] = v;
            }
          } else if (EPI == 2){
            if (col < HP){
              float o = (col < Hd) ? v + (bias ? bias[col] : 0.f) : 0.f;
              bf16 h = f2bf(o);
              size_t idx = tidxHP((int)rowg, col);
              Ybh[idx] = h;
              Ybl[idx] = f2bf(o - bf2f(h));
            }
          } else if (EPI == 3){
            Y[rowg*Nd + col] = v*scale + e0[b*Nd + col];
          } else if (EPI == 10){
            if (col < HP){
              float o = 0.f;
              if (col < Hd){
                float vv = v + (bias ? bias[col] : 0.f);
                o = 0.5f*vv*(1.f + erff(vv*0.7071067811865476f));
              }
              bf16 h = f2bf(o);
              size_t idx = tidxHP((int)rowg, col);
              Ybh[idx] = h;
              Ybl[idx] = f2bf(o - bf2f(h));
            }
          }
        }
      }
    }
  }
}

// ============================ split-K=4 MFMA GEMM (K=1024 mixes) ================
// EPI: 5 Y+=relu(acc/denom[row]) + pair   6 Y=acc*maskf[row]+R + pair
//      7 Y=acc*maskf[row]+Y + pair        8 pair only (ctx)
// Optional TbH/TbL: ALSO write the transposed tiled-1024 pair (d=col, k=row).
template<int EPI, int TERMS, int KP>
__global__ __launch_bounds__(256)
void k_mfma3sk(const bf16* __restrict__ Ah, const bf16* __restrict__ Al,
               const bf16* __restrict__ Bh, const bf16* __restrict__ Bl,
               float* __restrict__ Y, bf16* __restrict__ Ybh, bf16* __restrict__ Ybl,
               const float* __restrict__ e0, const float* __restrict__ e1,
               const float* __restrict__ R,
               size_t sAb, size_t sBb,
               bf16* __restrict__ TbH, bf16* __restrict__ TbL)
{
  __shared__ float red[4][64][33];
  int b = blockIdx.z;
  int wave = threadIdx.x >> 6, lane = threadIdx.x & 63;
  int r0 = blockIdx.x*32;
  int c0 = blockIdx.y*64;
  int lm = lane & 15, lq = lane >> 4;
  const size_t aT = (size_t)b*sAb + (size_t)(r0>>4)*((size_t)16*KP) + (size_t)lane*8;
  const size_t bT = (size_t)b*sBb + (size_t)(c0>>4)*((size_t)16*KP) + (size_t)lane*8;
  const int kt0 = wave*(KP>>7);
  constexpr int STEPS = KP/128;

  f32x4 acc[2][4] = {};
  bf16x8 pah[2][2], pal[2][2], pbh[2][4], pbl[2][4];
  {
    const size_t ko = (size_t)kt0*512;
    #pragma unroll
    for (int i = 0; i < 2; i++) pah[0][i] = *(const bf16x8*)(Ah + aT + (size_t)(i*16)*KP + ko);
    #pragma unroll
    for (int j = 0; j < 4; j++){
      pbh[0][j] = *(const bf16x8*)(Bh + bT + (size_t)(j*16)*KP + ko);
      pbl[0][j] = *(const bf16x8*)(Bl + bT + (size_t)(j*16)*KP + ko);
    }
    if (TERMS >= 3){
      #pragma unroll
      for (int i = 0; i < 2; i++) pal[0][i] = *(const bf16x8*)(Al + aT + (size_t)(i*16)*KP + ko);
    }
  }

  #pragma unroll
  for (int ki = 0; ki < STEPS; ki++){
    const int cb = ki & 1, nb = cb ^ 1;
    if (ki + 1 < STEPS){
      const size_t kn = (size_t)(kt0 + ki + 1)*512;
      #pragma unroll
      for (int i = 0; i < 2; i++) pah[nb][i] = *(const bf16x8*)(Ah + aT + (size_t)(i*16)*KP + kn);
      #pragma unroll
      for (int j = 0; j < 4; j++){
        pbh[nb][j] = *(const bf16x8*)(Bh + bT + (size_t)(j*16)*KP + kn);
        pbl[nb][j] = *(const bf16x8*)(Bl + bT + (size_t)(j*16)*KP + kn);
      }
      if (TERMS >= 3){
        #pragma unroll
        for (int i = 0; i < 2; i++) pal[nb][i] = *(const bf16x8*)(Al + aT + (size_t)(i*16)*KP + kn);
      }
    }
    #pragma unroll
    for (int i = 0; i < 2; i++)
      #pragma unroll
      for (int j = 0; j < 4; j++) acc[i][j] = MFMA16(pah[cb][i], pbh[cb][j], acc[i][j]);
    #pragma unroll
    for (int i = 0; i < 2; i++)
      #pragma unroll
      for (int j = 0; j < 4; j++) acc[i][j] = MFMA16(pah[cb][i], pbl[cb][j], acc[i][j]);
    if (TERMS >= 3){
      #pragma unroll
      for (int i = 0; i < 2; i++)
        #pragma unroll
        for (int j = 0; j < 4; j++) acc[i][j] = MFMA16(pal[cb][i], pbh[cb][j], acc[i][j]);
    }
  }

  #pragma unroll
  for (int i = 0; i < 2; i++)
    #pragma unroll
    for (int j = 0; j < 4; j++)
      #pragma unroll
      for (int r = 0; r < 4; r++)
        red[wave][lane][i*16 + j*4 + r] = acc[i][j][r];
  __syncthreads();

  int iw = wave >> 1, j0 = (wave & 1)*2;
  #pragma unroll
  for (int jj = 0; jj < 2; jj++){
    int j = j0 + jj;
    int col = c0 + j*16 + lm;
    #pragma unroll
    for (int r = 0; r < 4; r++){
      int f = iw*16 + j*4 + r;
      float v = red[0][lane][f] + red[1][lane][f] + red[2][lane][f] + red[3][lane][f];
      int row = r0 + iw*16 + lq*4 + r;
      size_t rowg = (size_t)b*Nd + row;
      if (col < HP){
        float nv = 0.f;
        if (EPI == 8){
          nv = (col < Hd) ? v : 0.f;
        } else if (EPI == 5){
          if (col < Hd){
            float u = v / e0[b*Nd+row]; u = u > 0.f ? u : 0.f;
            nv = Y[rowg*Hd + col] + u;
            Y[rowg*Hd + col] = nv;
          }
        } else if (EPI == 6){
          if (col < Hd){
            nv = v*e1[b*Nd+row] + R[rowg*Hd+col];
            Y[rowg*Hd + col] = nv;
          }
        } else if (EPI == 7){
          if (col < Hd){
            nv = v*e1[b*Nd+row] + Y[rowg*Hd+col];
            Y[rowg*Hd + col] = nv;
          }
        }
        bf16 h = f2bf(nv);
        bf16 lo = f2bf(nv - bf2f(h));
        size_t idx = tidxHP((int)rowg, col);
        Ybh[idx] = h; Ybl[idx] = lo;
        if (TbH != nullptr){
          size_t idx2 = (size_t)b*((size_t)HP*Nd) + tidx1024(col, row);
          TbH[idx2] = h; TbL[idx2] = lo;
        }
      }
    }
  }
}

// ============================ host launch ============================
static inline char* carve(char*& p, size_t bytes){
  char* r = p;
  p += (bytes + 511) & ~(size_t)511;
  return r;
}

extern "C" void kernel_launch(void* const* d_in, const int* in_sizes, int n_in,
                              void* d_out, int out_size, void* d_ws, size_t ws_size,
                              hipStream_t stream){
  (void)in_sizes; (void)n_in; (void)out_size; (void)ws_size;
  const float* text     = (const float*)d_in[0];
  const float* adj1     = (const float*)d_in[1];
  const float* adj2     = (const float*)d_in[2];
  const float* textmask = (const float*)d_in[5];
  const float* gcn_w    = (const float*)d_in[6];
  const float* mut_w    = (const float*)d_in[7];
  const float* qw = (const float*)d_in[8],  *qb = (const float*)d_in[9];
  const float* kw = (const float*)d_in[10], *kb = (const float*)d_in[11];
  const float* vw = (const float*)d_in[12], *vb = (const float*)d_in[13];
  const float* aow= (const float*)d_in[14], *aob= (const float*)d_in[15];
  const float* g1 = (const float*)d_in[16], *b1 = (const float*)d_in[17];
  const float* iw = (const float*)d_in[18], *ib = (const float*)d_in[19];
  const float* ow = (const float*)d_in[20], *ob = (const float*)d_in[21];
  const float* g2 = (const float*)d_in[22], *b2 = (const float*)d_in[23];

  float* out_outs = (float*)d_out;
  float* out_adj  = out_outs + SZ_BNH;

  // ---- workspace carve (~190 MB). out_outs doubles as fp32 scratch sc2. ----
  char* p = (char*)d_ws;
  float* cur  = (float*)carve(p, SZ_BNH*4);
  float* sc1  = (float*)carve(p, SZ_BNH*4);
  float* fo   = (float*)carve(p, SZ_BNH*4);
  float* S    = (float*)carve(p, SZ_BNN*4);           // fp32 scores / logits
  bf16*  Rb   = (bf16*)carve(p, SZ_BNN*2*2);          // attnP / p_row pair
  bf16*  Rc   = (bf16*)carve(p, SZ_BNN*2*2);          // p_col^T pair
  bf16*  T1   = (bf16*)carve(p, SZ_PAD*2);
  bf16*  T2   = (bf16*)carve(p, SZ_PAD*2);
  bf16*  T3   = (bf16*)carve(p, SZ_PAD*2);
  bf16*  T4   = (bf16*)carve(p, SZ_PAD*2);
  bf16*  T5   = (bf16*)carve(p, SZ_PAD*2);
  bf16*  T6   = (bf16*)carve(p, SZ_PAD*2);
  bf16*  TA1  = (bf16*)carve(p, SZ_PAD*2);            // cur / new_outs pair
  bf16*  TA2  = (bf16*)carve(p, SZ_PAD*2);
  bf16*  TF1  = (bf16*)carve(p, SZ_PAD*2);            // fo pair (row-tiled)
  bf16*  TF2  = (bf16*)carve(p, SZ_PAD*2);
  bf16*  TT1  = (bf16*)carve(p, SZ_PAD*2);            // fo^T pair (from sk5)
  bf16*  TT2  = (bf16*)carve(p, SZ_PAD*2);
  bf16*  ADJB = (bf16*)carve(p, SZ_BNN*2);            // adj bf16 tiled (const)
  bf16*  Wh_all = (bf16*)carve(p, (size_t)21*HP*HP*2);   // +1 slack slot
  bf16*  Wl_all = (bf16*)carve(p, (size_t)21*HP*HP*2);
  float* cpm     = (float*)carve(p, (size_t)8*BN*4);  // col-stat partials
  float* cps     = (float*)carve(p, (size_t)8*BN*4);
  float* denom   = (float*)carve(p, BN*4);
  float* maskf   = (float*)carve(p, BN*4);
  float* maskadd = (float*)carve(p, BN*4);
  float* cmaxv   = (float*)carve(p, BN*4);
  float* csumv   = (float*)carve(p, BN*4);

  float* sc2 = out_outs;          // fp32 scratch; final sk6 overwrites in iter 2
  bf16* attnP = Rb;
  bf16* Ph    = Rb;
  bf16* Pl    = Rb + SZ_BNN;
  bf16* PcH   = Rc;
  bf16* PcL   = Rc + SZ_BNN;

  const size_t sNT = (size_t)Nd*HP;     // batch stride (tiled), 1024*224
  const size_t sT  = (size_t)HP*Nd;     // batch stride (tiled), 224*1024
  const size_t sNN = (size_t)Nd*Nd;     // batch stride, 1024*1024

  #define W_GCN 0
  #define W_MUT 1
  #define W_Q(i) (2 + (i))
  #define W_K(i) (5 + (i))
  #define W_V(i) (8 + (i))
  #define W_AO(i) (11 + (i))
  #define W_IW(i) (14 + (i))
  #define W_OW(i) (17 + (i))
  #define WH(s) (Wh_all + (size_t)(s)*HP*HP)
  #define WL(s) (Wl_all + (size_t)(s)*HP*HP)

  dim3 blk256(256);
  dim3 gPad((unsigned)((SZ_PAD+255)/256));
  dim3 gPadT(32, 7, Bd), bT(32, 8);
  dim3 gWall((HP*HP+255)/256, 20);
  dim3 gCvt(32, 128, Bd);
  dim3 gBNH((unsigned)((SZ_BNH+255)/256));
  dim3 gSm(4, 128, 1);       // small GEMM: 16x64/wave (RI=1), 8192 rows, K=HP
  dim3 gQKV(4, 128, 3);      // merged Q/K/V
  dim3 gNT(16, 8, Bd);       // scores/logits: 32x64/wave (RI=2), K=HP
  dim3 gSK(32, 4, Bd);       // split-K=4 mixes: 32-row blocks
  const float inv_sqrt_h = 0.07071067811865475f;  // 1/sqrt(200)
  const size_t Z = 0;
  float* FN = nullptr;
  bf16*  BN_ = nullptr;

  k_prep_masks<<<(BN+255)/256, blk256, 0, stream>>>(textmask, maskf, maskadd);
  k_prep_adj<<<BN, blk256, 0, stream>>>(adj1, adj2, out_adj, denom);
  k_copy2<<<gBNH, blk256, 0, stream>>>(text, cur, fo);
  c_w_split_all<<<gWall, blk256, 0, stream>>>(gcn_w, mut_w, qw, kw, vw, aow, iw, ow,
                                              Wh_all, Wl_all);
  c_pad_split<<<gPad, blk256, 0, stream>>>(text, TA1, TA2);   // BERT-in pair (iter 0)
  c_pad_split<<<gPad, blk256, 0, stream>>>(text, TF1, TF2);   // fo pair (iter 0)
  c_cvt1024_t<<<gCvt, blk256, 0, stream>>>(out_adj, ADJB);    // adj bf16 (const)

  for (int i = 0; i < 3; i++){
    const float *qbi = qb + i*Hd;
    const float *kbi = kb + i*Hd;
    const float *vbi = vb + i*Hd;
    const float *aobi= aob+ i*Hd;
    const float *g1i = g1 + i*Hd,    *b1i = b1 + i*Hd;
    const float *ibi = ib + i*Hd;
    const float *obi = ob + i*Hd;
    const float *g2i = g2 + i*Hd,    *b2i = b2 + i*Hd;

    // ================= BERT layer =================
    k_qkv<<<gQKV, blk256, 0, stream>>>(TA1,TA2, WH(W_Q(i)),WL(W_Q(i)),
              T3,T4, T5,T6, T1,T2, qbi,kbi,vbi);                            // Q,K pairs + V^T pair
    k_mfma3<3,3,2,HP><<<gNT, blk256, 0, stream>>>(T3,T4,T5,T6, S,BN_,BN_,
              nullptr, maskadd,nullptr, sNT,sNT, inv_sqrt_h, FN,FN);        // scores
    k_rowsoftmax0<<<BN, blk256, 0, stream>>>(S, attnP);                     // attn probs
    k_mfma3sk<8,2,Nd><<<gSK, blk256, 0, stream>>>(attnP,BN_,T1,T2,
              FN,T3,T4, FN,FN,FN, sNN,sT, BN_,BN_);                         // ctx pair
    k_mfma3<0,3,1,HP><<<gSm, blk256, 0, stream>>>(T3,T4,WH(W_AO(i)),WL(W_AO(i)),
              sc1,BN_,BN_, aobi, FN,FN, Z,Z, 0.f, FN,FN);                   // ao_out fp32
    k_add_ln<<<BN, blk256, 0, stream>>>(sc1, cur, g1i, b1i, sc2, T1, T2);   // ln1 + pair
    k_mfma3<10,3,1,HP><<<gSm, blk256, 0, stream>>>(T1,T2,WH(W_IW(i)),WL(W_IW(i)),
              FN,T3,T4, ibi, FN,FN, Z,Z, 0.f, FN,FN);                       // gelu pair
    k_mfma3<0,3,1,HP><<<gSm, blk256, 0, stream>>>(T3,T4,WH(W_OW(i)),WL(W_OW(i)),
              cur,BN_,BN_, obi, FN,FN, Z,Z, 0.f, FN,FN);                    // ow_out fp32
    k_add_ln<<<BN, blk256, 0, stream>>>(cur, sc2, g2i, b2i, cur, TA1, TA2); // ln2 + pair

    // ================= GCN on fo =================
    k_mfma3<9,3,1,HP><<<gSm, blk256, 0, stream>>>(TF1,TF2,WH(W_GCN),WL(W_GCN),
              FN,T1,T2, nullptr, FN,FN, Z,Z, 0.f, FN,FN);                   // teout^T pair
    k_mfma3sk<5,2,Nd><<<gSK, blk256, 0, stream>>>(ADJB,BN_,T1,T2,
              fo,TF1,TF2, denom,FN,FN, sNN,sT, TT1,TT2);                    // fo update + pair + fo^T

    // ================= self-alignment =================
    k_mfma3<2,3,1,HP><<<gSm, blk256, 0, stream>>>(TA1,TA2,WH(W_MUT),WL(W_MUT),
              FN,T5,T6, nullptr, FN,FN, Z,Z, 0.f, FN,FN);                   // mm pair
    k_mfma3<4,3,2,HP><<<gNT, blk256, 0, stream>>>(T5,T6,TF1,TF2, S,BN_,BN_,
              nullptr, nullptr,maskf, sNT,sNT, 0.f, cpm,cps);               // logits + col partials
    k_colcomb<<<BN/256, blk256, 0, stream>>>(cpm, cps, cmaxv, csumv);
    k_rowsm8<<<BN/8, blk256, 0, stream>>>(S, Ph, Pl, cmaxv, csumv, PcH, PcL);
    c_padT_split<<<gPadT, bT, 0, stream>>>(cur, T3, T4);                    // outs^T (POST-BERT cur)
    k_mfma3sk<6,3,Nd><<<gSK, blk256, 0, stream>>>(Ph,Pl,TT1,TT2,
              (i==2)?out_outs:sc1, TA1,TA2, FN,maskf,cur, sNN,sT, BN_,BN_); // new_outs + pair
    k_mfma3sk<7,3,Nd><<<gSK, blk256, 0, stream>>>(PcH,PcL,T3,T4,
              fo,TF1,TF2, FN,maskf,FN, sNN,sT, BN_,BN_);                    // fo update + pair

    float* t = cur; cur = sc1; sc1 = t;          // outs = new_outs (fp32 chain)
  }
}